// Round 13
// baseline (626.899 us; speedup 1.0000x reference)
//
#include <hip/hip_runtime.h>
#include <hip/hip_bf16.h>

typedef __attribute__((ext_vector_type(4))) short short4v;
typedef __attribute__((ext_vector_type(8))) short short8v;
typedef __attribute__((ext_vector_type(16))) float f32x16;

union frag8 { short8v v8; struct { short4v lo, hi; } p; };

__device__ __forceinline__ unsigned short f2bf(float v) {
  unsigned u = __float_as_uint(v);
  unsigned r = u + 0x7fffu + ((u >> 16) & 1u);
  return (unsigned short)(r >> 16);
}
__device__ __forceinline__ float bf2f(unsigned short h) {
  return __uint_as_float(((unsigned)h) << 16);
}

// ---------------- conv1: one block per (b,h), LDS input slab, weights in regs ----------------
__global__ __launch_bounds__(192) void conv1_fused(const float* __restrict__ images,
                                                   const float* __restrict__ w1,
                                                   float* __restrict__ out) {
  int b = blockIdx.x >> 5, h = blockIdx.x & 31;
  __shared__ __align__(16) float lin[3][3][36];
  int tid = threadIdx.x;
  for (int e = tid; e < 324; e += 192) {
    int ci = e / 108, rem = e % 108, ki = rem / 36, wi = rem % 36;
    int row = h + ki - 1, col = wi - 1;
    float v = 0.f;
    if (row >= 0 && row < 32 && col >= 0 && col < 32)
      v = images[((size_t)(b*3 + ci)*32 + row)*32 + col];
    lin[ci][ki][wi] = v;
  }
  int co = tid >> 2, ws = tid & 3;
  float wr[27];
  #pragma unroll
  for (int j = 0; j < 27; ++j) wr[j] = w1[co*27 + j];
  __syncthreads();
  float o[8];
  #pragma unroll
  for (int j = 0; j < 8; ++j) o[j] = 0.f;
  #pragma unroll
  for (int ci = 0; ci < 3; ++ci)
    #pragma unroll
    for (int ki = 0; ki < 3; ++ki) {
      float4 q0 = *(const float4*)&lin[ci][ki][ws*8];
      float4 q1 = *(const float4*)&lin[ci][ki][ws*8+4];
      float4 q2 = *(const float4*)&lin[ci][ki][ws*8+8];
      float r[12] = {q0.x,q0.y,q0.z,q0.w,q1.x,q1.y,q1.z,q1.w,q2.x,q2.y,q2.z,q2.w};
      #pragma unroll
      for (int kj = 0; kj < 3; ++kj) {
        float wv = wr[(ci*3+ki)*3+kj];
        #pragma unroll
        for (int j = 0; j < 8; ++j) o[j] = fmaf(r[j+kj], wv, o[j]);
      }
    }
  float* dst = out + (((size_t)(b*48+co)*32 + h)*32 + ws*8);
  *(float4*)dst       = make_float4(o[0],o[1],o[2],o[3]);
  *(float4*)(dst + 4) = make_float4(o[4],o[5],o[6],o[7]);
}

// ---------------- merged weight split+reorder for conv2/conv3/primary ----------------
__device__ __forceinline__ void split_one(const float* w, unsigned short* wh,
                                          unsigned short* wl, int CI, int i) {
  int K = CI*9;
  int co = i / K, rem = i % K, tap = rem / CI, ci = rem % CI;
  float v = w[(co*CI + ci)*9 + tap];
  unsigned short h = f2bf(v);
  wh[i] = h;
  wl[i] = f2bf(v - bf2f(h));
}
__global__ void split_w_all(const float* __restrict__ w2, const float* __restrict__ w3,
                            const float* __restrict__ wp,
                            unsigned short* wh2, unsigned short* wl2,
                            unsigned short* wh3, unsigned short* wl3,
                            unsigned short* whp, unsigned short* wlp) {
  int i = blockIdx.x*256 + threadIdx.x;
  if (i < 41472) split_one(w2, wh2, wl2, 48, i);
  else if (i < 207360) split_one(w3, wh3, wl3, 96, i - 41472);
  else if (i < 539136) split_one(wp, whp, wlp, 192, i - 207360);
}

// ---------------- BN affine + ReLU + split to padded NHWC bf16 hi/lo (writes halos) ----------------
template<int C,int H,int W,int P>
__global__ void bn_split_nhwc(const float* __restrict__ in, const float* __restrict__ sc,
                              unsigned short* __restrict__ xh, unsigned short* __restrict__ xl) {
  constexpr int HP = H + 2*P, WP = W + 2*P;
  int b = blockIdx.x / HP, hp = blockIdx.x % HP;
  int h = hp - P;
  for (int e = threadIdx.x; e < WP*C; e += 256) {
    int wp = e / C, c = e % C;
    int w = wp - P;
    float v = 0.f;
    if (h >= 0 && h < H && w >= 0 && w < W) {
      v = in[((size_t)(b*C + c)*H + h)*W + w];
      v = fmaf(v, sc[c*2], sc[c*2+1]);
      v = v > 0.f ? v : 0.f;
    }
    unsigned short hh = f2bf(v);
    size_t o = ((size_t)(b*HP + hp)*WP + wp)*C + c;
    xh[o] = hh;
    xl[o] = f2bf(v - bf2f(hh));
  }
}

// ---------------- MFMA implicit-GEMM conv; SPLITK==1 writes NCHW directly ----------------
template<int CI,int HIP,int WIP,int HO,int WO,int STR,int SPLITK>
__global__ __launch_bounds__(256,4) void conv_mfma(
    const unsigned short* __restrict__ xh, const unsigned short* __restrict__ xl,
    const unsigned short* __restrict__ wh, const unsigned short* __restrict__ wl,
    float* __restrict__ part, int CO, int B) {
  constexpr int K = CI*9, NSP = HO*WO, KCH = K/SPLITK, LDA = 36;
  const int NTOT = B*NSP;
  const int m0 = blockIdx.x*64, n0 = blockIdx.y*128, ks = blockIdx.z;
  __shared__ unsigned short Ah[64*LDA], Al[64*LDA], Bh[128*LDA], Bl[128*LDA];
  const int tid = threadIdx.x, lane = tid & 63, wid = tid >> 6;
  const int wm = wid >> 1, wn = wid & 1;
  const int arow = tid >> 2, ak0 = (tid & 3)*8;
  const bool aok = (m0 + arow) < CO;
  const size_t abase = (size_t)(m0 + arow)*K;
  int brow[2], bk0[2];
  size_t bbase[2];
  #pragma unroll
  for (int i = 0; i < 2; ++i) {
    int e = tid + i*256;
    brow[i] = e >> 2; bk0[i] = (e & 3)*8;
    int nn = n0 + brow[i]; if (nn > NTOT-1) nn = NTOT-1;
    int bb = nn / NSP, sp = nn % NSP;
    int ho = sp / WO, wo = sp % WO;
    bbase[i] = ((size_t)bb*HIP + ho*STR)*WIP + wo*STR;
  }
  f32x16 acc0 = (f32x16)0.f, acc1 = (f32x16)0.f;
  const int kBeg = ks*KCH, kEnd = kBeg + KCH;
  for (int kc = kBeg; kc < kEnd; kc += 32) {
    const int kLim = (kEnd - kc) < 32 ? (kEnd - kc) : 32;
    {
      frag8 vh, vl;
      vh.v8 = (short8v)(short)0; vl.v8 = (short8v)(short)0;
      if (aok && ak0 < kLim) {
        size_t off = abase + kc + ak0;
        vh.v8 = *(const short8v*)(wh + off);
        vl.v8 = *(const short8v*)(wl + off);
      }
      int lo_ = arow*LDA + ak0;
      *(short4v*)(Ah + lo_) = vh.p.lo; *(short4v*)(Ah + lo_ + 4) = vh.p.hi;
      *(short4v*)(Al + lo_) = vl.p.lo; *(short4v*)(Al + lo_ + 4) = vl.p.hi;
    }
    #pragma unroll
    for (int i = 0; i < 2; ++i) {
      frag8 vh, vl;
      vh.v8 = (short8v)(short)0; vl.v8 = (short8v)(short)0;
      if (bk0[i] < kLim) {
        int kg = kc + bk0[i];
        int tap = kg / CI, ci0 = kg - tap*CI;
        int dh = tap / 3, dw = tap - dh*3;
        size_t off = (bbase[i] + (size_t)dh*WIP + dw)*CI + ci0;
        vh.v8 = *(const short8v*)(xh + off);
        vl.v8 = *(const short8v*)(xl + off);
      }
      int lo_ = brow[i]*LDA + bk0[i];
      *(short4v*)(Bh + lo_) = vh.p.lo; *(short4v*)(Bh + lo_ + 4) = vh.p.hi;
      *(short4v*)(Bl + lo_) = vl.p.lo; *(short4v*)(Bl + lo_ + 4) = vl.p.hi;
    }
    __syncthreads();
    #pragma unroll
    for (int kst = 0; kst < 2; ++kst) {
      const int kb = kst*16 + 8*(lane >> 5);
      const int ar = wm*32 + (lane & 31);
      frag8 ah, al;
      { int o = ar*LDA + kb;
        ah.p.lo = *(const short4v*)(Ah + o); ah.p.hi = *(const short4v*)(Ah + o + 4);
        al.p.lo = *(const short4v*)(Al + o); al.p.hi = *(const short4v*)(Al + o + 4); }
      const int br = wn*64 + (lane & 31);
      frag8 bh0, bl0, bh1, bl1;
      { int o = br*LDA + kb;
        bh0.p.lo = *(const short4v*)(Bh + o); bh0.p.hi = *(const short4v*)(Bh + o + 4);
        bl0.p.lo = *(const short4v*)(Bl + o); bl0.p.hi = *(const short4v*)(Bl + o + 4); }
      { int o = (br+32)*LDA + kb;
        bh1.p.lo = *(const short4v*)(Bh + o); bh1.p.hi = *(const short4v*)(Bh + o + 4);
        bl1.p.lo = *(const short4v*)(Bl + o); bl1.p.hi = *(const short4v*)(Bl + o + 4); }
      acc0 = __builtin_amdgcn_mfma_f32_32x32x16_bf16(ah.v8, bh0.v8, acc0, 0, 0, 0);
      acc0 = __builtin_amdgcn_mfma_f32_32x32x16_bf16(ah.v8, bl0.v8, acc0, 0, 0, 0);
      acc0 = __builtin_amdgcn_mfma_f32_32x32x16_bf16(al.v8, bh0.v8, acc0, 0, 0, 0);
      acc1 = __builtin_amdgcn_mfma_f32_32x32x16_bf16(ah.v8, bh1.v8, acc1, 0, 0, 0);
      acc1 = __builtin_amdgcn_mfma_f32_32x32x16_bf16(ah.v8, bl1.v8, acc1, 0, 0, 0);
      acc1 = __builtin_amdgcn_mfma_f32_32x32x16_bf16(al.v8, bh1.v8, acc1, 0, 0, 0);
    }
    __syncthreads();
  }
  #pragma unroll
  for (int ns = 0; ns < 2; ++ns) {
    f32x16 a = ns ? acc1 : acc0;
    #pragma unroll
    for (int r = 0; r < 16; ++r) {
      int row = (r & 3) + 8*(r >> 2) + 4*(lane >> 5);
      int m = m0 + wm*32 + row;
      int n = n0 + wn*64 + ns*32 + (lane & 31);
      if (m < CO && n < NTOT) {
        if (SPLITK == 1) {
          int b = n / NSP, sp = n % NSP;
          part[((size_t)b*CO + m)*NSP + sp] = a[r];
        } else {
          part[((size_t)ks*CO + m)*NTOT + n] = a[r];
        }
      }
    }
  }
}

// ---------------- split-K reduce (+bias, + optional fused BN partial stats) ----------------
template<int CO,int NSP,int SPLITK,bool BIAS,bool STATS>
__global__ void splitk_reduce(const float* __restrict__ part, const float* __restrict__ bias,
                              float* __restrict__ out, float* __restrict__ stats, int B) {
  const int NTOT = B*NSP;
  int i = blockIdx.x*256 + threadIdx.x;
  bool valid = i < CO*NTOT;
  float s = 0.f;
  if (valid) {
    int co = i / NTOT, n = i % NTOT;
    #pragma unroll
    for (int ks = 0; ks < SPLITK; ++ks) s += part[(size_t)(ks*CO + co)*NTOT + n];
    if (BIAS) s += bias[co];
    int b = n / NSP, sp = n % NSP;
    out[((size_t)b*CO + co)*NSP + sp] = s;
  }
  if (STATS) {
    float sum = valid ? s : 0.f, sq = valid ? s*s : 0.f;
    #pragma unroll
    for (int off = 32; off; off >>= 1) {
      sum += __shfl_down(sum, off, 64);
      sq  += __shfl_down(sq,  off, 64);
    }
    __shared__ float ls[2][4];
    int lane = threadIdx.x & 63, wv = threadIdx.x >> 6;
    if (lane == 0) { ls[0][wv] = sum; ls[1][wv] = sq; }
    __syncthreads();
    if (threadIdx.x == 0) {
      float S = 0.f, Q = 0.f;
      #pragma unroll
      for (int j = 0; j < 4; ++j) { S += ls[0][j]; Q += ls[1][j]; }
      int bpc = NTOT/256;
      int co = blockIdx.x / bpc, slice = blockIdx.x % bpc;
      stats[(co*bpc + slice)*2 + 0] = S;
      stats[(co*bpc + slice)*2 + 1] = Q;
    }
  }
}

// ---------------- BN stats ----------------
template<int C,int HW,int SLICES>
__global__ void bn_partial(const float* __restrict__ x, float* __restrict__ part, int B) {
  int c = blockIdx.x / SLICES, s = blockIdx.x % SLICES;
  int bpp = B / SLICES;
  float sum = 0.f, sq = 0.f;
  for (int b = s*bpp; b < (s+1)*bpp; ++b) {
    const float* p = x + ((size_t)b*C + c)*HW;
    for (int i = threadIdx.x; i < HW; i += blockDim.x) {
      float v = p[i]; sum += v; sq += v*v;
    }
  }
  #pragma unroll
  for (int off = 32; off; off >>= 1) {
    sum += __shfl_down(sum, off, 64);
    sq  += __shfl_down(sq,  off, 64);
  }
  __shared__ float ls[2][4];
  int lane = threadIdx.x & 63, wv = threadIdx.x >> 6;
  if (lane == 0) { ls[0][wv] = sum; ls[1][wv] = sq; }
  __syncthreads();
  if (threadIdx.x == 0) {
    float S = 0.f, Q = 0.f;
    #pragma unroll
    for (int i = 0; i < 4; ++i) { S += ls[0][i]; Q += ls[1][i]; }
    part[(c*SLICES+s)*2+0] = S; part[(c*SLICES+s)*2+1] = Q;
  }
}

template<int C,int SLICES>
__global__ void bn_final(const float* __restrict__ part, const float* __restrict__ g,
                         const float* __restrict__ bta, float* __restrict__ sc, int NHW) {
  int c = blockIdx.x*blockDim.x + threadIdx.x;
  if (c >= C) return;
  float S = 0.f, Q = 0.f;
  for (int s = 0; s < SLICES; ++s) { S += part[(c*SLICES+s)*2]; Q += part[(c*SLICES+s)*2+1]; }
  float m = S / NHW, v = Q / NHW - m*m;
  float inv = rsqrtf(v + 1e-5f);
  float a = g[c] * inv;
  sc[c*2] = a; sc[c*2+1] = bta[c] - m*a;
}

// ---------------- squash primary caps in place ----------------
__global__ void squash_pc(float* __restrict__ pc, int ncaps) {
  int i = blockIdx.x*blockDim.x + threadIdx.x;
  if (i >= ncaps) return;
  float* p = pc + (size_t)i*12;
  float v[12]; float s = 0.f;
  #pragma unroll
  for (int d = 0; d < 12; ++d) { v[d] = p[d]; s += v[d]*v[d]; }
  float sc = s / ((1.f + s)*sqrtf(s + 1e-6f));
  #pragma unroll
  for (int d = 0; d < 12; ++d) p[d] = v[d]*sc;
}

// ---------------- uu gather ----------------
__global__ void uu_gather(const float* __restrict__ sq, float* __restrict__ uu, int B) {
  int idx = blockIdx.x*blockDim.x + threadIdx.x;
  int total = B*49*144*12;
  if (idx >= total) return;
  int ii = idx % 12; int t0 = idx / 12;
  int kk = t0 % 144; t0 /= 144;
  int tt = t0 % 49;  int b = t0 / 49;
  int f = tt*1728 + kk*12 + ii;
  int c = f / 441; int r = f - c*441;
  int k = r / 49;  int sp = r - k*49;
  int y = sp / 7, x = sp - y*7;
  int iy = y + k/3 - 1, ix = x + (k%3) - 1;
  float val = 0.f;
  if (iy >= 0 && iy < 7 && ix >= 0 && ix < 7)
    val = sq[((size_t)(b*192 + c)*7 + iy)*7 + ix];
  uu[idx] = val;
}

// ---------------- ConvCaps einsum: 4 o's + 16 m's per thread, ushort4 stores ----------------
__global__ __launch_bounds__(192) void cc_einsum3(const float* __restrict__ uu,
                                                  const float* __restrict__ wcc,
                                                  __hip_bfloat16* __restrict__ uhat,
                                                  int row0, int nrows) {
  const int k  = blockIdx.x;
  const int m0 = blockIdx.y * 64;
  const int tid = threadIdx.x;
  const int m4 = tid / 48, oq = tid % 48;
  float wr[4][12];
  #pragma unroll
  for (int c = 0; c < 4; ++c) {
    const float4* wp4 = (const float4*)(wcc + ((size_t)k*192 + oq*4 + c)*12);
    float4 a = wp4[0], b = wp4[1], d = wp4[2];
    wr[c][0]=a.x; wr[c][1]=a.y; wr[c][2]=a.z; wr[c][3]=a.w;
    wr[c][4]=b.x; wr[c][5]=b.y; wr[c][6]=b.z; wr[c][7]=b.w;
    wr[c][8]=d.x; wr[c][9]=d.y; wr[c][10]=d.z; wr[c][11]=d.w;
  }
  int mmax = nrows - m0; if (mmax > 64) mmax = 64;
  #pragma unroll 4
  for (int mi = 0; mi < 16; ++mi) {
    int m = m4*16 + mi;
    if (m >= mmax) break;
    const float4* ar = (const float4*)(uu + ((size_t)(row0+m0+m)*144 + k)*12);
    float4 a0 = ar[0], a1 = ar[1], a2 = ar[2];
    float af[12] = {a0.x,a0.y,a0.z,a0.w,a1.x,a1.y,a1.z,a1.w,a2.x,a2.y,a2.z,a2.w};
    ushort4 pkt;
    unsigned short* pp = (unsigned short*)&pkt;
    #pragma unroll
    for (int c = 0; c < 4; ++c) {
      float acc = 0.f;
      #pragma unroll
      for (int i = 0; i < 12; ++i) acc = fmaf(wr[c][i], af[i], acc);
      pp[c] = f2bf(acc);
    }
    unsigned short* up = (unsigned short*)uhat + ((size_t)(m0+m)*144 + k)*192 + oq*4;
    *(ushort4*)up = pkt;
  }
}

// ---------------- ConvCaps routing: small register stash (24 groups), fused 3-pass -----------
// 384 threads = 24 groups x 16 lanes. lane=(g,oc); group g owns k = g+24j, j=0..5.
__global__ __launch_bounds__(384,8) void cc_route(const __hip_bfloat16* __restrict__ uhat,
                                                  float* __restrict__ u2, int rowOff) {
  const int row = blockIdx.x;
  const unsigned short* __restrict__ uh = (const unsigned short*)uhat + (size_t)row*27648;
  __shared__ float red[6][192];
  __shared__ float sraw[192];
  __shared__ float vsh[192];
  const int tid = threadIdx.x, lane = tid & 63, wv = tid >> 6;
  const int g = tid >> 4, oc = tid & 15;
  uint2 st[6][3];
  float blog[6];
  #pragma unroll
  for (int j = 0; j < 6; ++j) blog[j] = 0.f;
  float sacc[12];

  // ---- pass 0: load + stash + uniform-c sum
  #pragma unroll
  for (int d = 0; d < 12; ++d) sacc[d] = 0.f;
  #pragma unroll
  for (int j = 0; j < 6; ++j) {
    const unsigned short* up = uh + (g + 24*j)*192 + oc*12;
    uint2 q0 = *(const uint2*)up;
    uint2 q1 = *(const uint2*)(up + 4);
    uint2 q2 = *(const uint2*)(up + 8);
    st[j][0] = q0; st[j][1] = q1; st[j][2] = q2;
    sacc[0] += bf2f((unsigned short)(q0.x & 0xffff)); sacc[1] += bf2f((unsigned short)(q0.x >> 16));
    sacc[2] += bf2f((unsigned short)(q0.y & 0xffff)); sacc[3] += bf2f((unsigned short)(q0.y >> 16));
    sacc[4] += bf2f((unsigned short)(q1.x & 0xffff)); sacc[5] += bf2f((unsigned short)(q1.x >> 16));
    sacc[6] += bf2f((unsigned short)(q1.y & 0xffff)); sacc[7] += bf2f((unsigned short)(q1.y >> 16));
    sacc[8] += bf2f((unsigned short)(q2.x & 0xffff)); sacc[9] += bf2f((unsigned short)(q2.x >> 16));
    sacc[10] += bf2f((unsigned short)(q2.y & 0xffff)); sacc[11] += bf2f((unsigned short)(q2.y >> 16));
  }
  #pragma unroll
  for (int d = 0; d < 12; ++d) {
    sacc[d] += __shfl_xor(sacc[d], 16, 64);
    sacc[d] += __shfl_xor(sacc[d], 32, 64);
  }
  if (lane < 16) {
    #pragma unroll
    for (int d = 0; d < 12; ++d) red[wv][oc*12 + d] = sacc[d];
  }
  __syncthreads();
  if (tid < 192) {
    float s = (red[0][tid] + red[1][tid] + red[2][tid]
             + red[3][tid] + red[4][tid] + red[5][tid]) * 0.0625f;
    sraw[tid] = s;
  }
  __syncthreads();
  if (tid < 192) {
    int qc = tid / 12;
    float nrm = 0.f;
    #pragma unroll
    for (int d = 0; d < 12; ++d) { float v = sraw[qc*12 + d]; nrm += v*v; }
    float sc = nrm / ((1.f + nrm)*sqrtf(nrm + 1e-6f));
    vsh[tid] = sraw[tid]*sc;
  }
  __syncthreads();

  // ---- passes 1,2: all-register data
  #pragma unroll
  for (int r = 1; r < 3; ++r) {
    float vq[12];
    #pragma unroll
    for (int d = 0; d < 12; ++d) vq[d] = vsh[oc*12 + d];
    #pragma unroll
    for (int d = 0; d < 12; ++d) sacc[d] = 0.f;
    #pragma unroll
    for (int j = 0; j < 6; ++j) {
      uint2 q0 = st[j][0], q1 = st[j][1], q2 = st[j][2];
      float uf[12];
      uf[0] = bf2f((unsigned short)(q0.x & 0xffff)); uf[1] = bf2f((unsigned short)(q0.x >> 16));
      uf[2] = bf2f((unsigned short)(q0.y & 0xffff)); uf[3] = bf2f((unsigned short)(q0.y >> 16));
      uf[4] = bf2f((unsigned short)(q1.x & 0xffff)); uf[5] = bf2f((unsigned short)(q1.x >> 16));
      uf[6] = bf2f((unsigned short)(q1.y & 0xffff)); uf[7] = bf2f((unsigned short)(q1.y >> 16));
      uf[8] = bf2f((unsigned short)(q2.x & 0xffff)); uf[9] = bf2f((unsigned short)(q2.x >> 16));
      uf[10] = bf2f((unsigned short)(q2.y & 0xffff)); uf[11] = bf2f((unsigned short)(q2.y >> 16));
      float dot = 0.f;
      #pragma unroll
      for (int d = 0; d < 12; ++d) dot = fmaf(vq[d], uf[d], dot);
      blog[j] += dot;
      float mx = blog[j];
      #pragma unroll
      for (int off = 1; off < 16; off <<= 1) mx = fmaxf(mx, __shfl_xor(mx, off, 16));
      float e = __expf(blog[j] - mx);
      float es = e;
      #pragma unroll
      for (int off = 1; off < 16; off <<= 1) es += __shfl_xor(es, off, 16);
      float c = e / es;
      #pragma unroll
      for (int d = 0; d < 12; ++d) sacc[d] = fmaf(c, uf[d], sacc[d]);
    }
    #pragma unroll
    for (int d = 0; d < 12; ++d) {
      sacc[d] += __shfl_xor(sacc[d], 16, 64);
      sacc[d] += __shfl_xor(sacc[d], 32, 64);
    }
    if (lane < 16) {
      #pragma unroll
      for (int d = 0; d < 12; ++d) red[wv][oc*12 + d] = sacc[d];
    }
    __syncthreads();
    if (tid < 192) {
      sraw[tid] = red[0][tid] + red[1][tid] + red[2][tid]
                + red[3][tid] + red[4][tid] + red[5][tid];
    }
    __syncthreads();
    if (tid < 192) {
      int qc = tid / 12;
      float nrm = 0.f;
      #pragma unroll
      for (int d = 0; d < 12; ++d) { float v = sraw[qc*12 + d]; nrm += v*v; }
      float sc = nrm / ((1.f + nrm)*sqrtf(nrm + 1e-6f));
      vsh[tid] = sraw[tid]*sc;
    }
    __syncthreads();
  }
  if (tid < 192) u2[((size_t)(rowOff + row))*192 + tid] = vsh[tid];
}

// ---------------- Class caps einsum (bf16 output) ----------------
__global__ void class_einsum(const float* __restrict__ u2, const float* __restrict__ wcl,
                             unsigned short* __restrict__ uhat2, int B) {
  int n = blockIdx.x;
  __shared__ float u2l[64][12];
  int tid = threadIdx.x;
  for (int e = tid; e < 64*12; e += 320) {
    int b = e / 12, i = e % 12;
    u2l[b][i] = u2[(size_t)b*9408 + n*12 + i];
  }
  __syncthreads();
  int od = tid % 160, bh = tid / 160;
  int o = od >> 4, d = od & 15;
  float w[12];
  #pragma unroll
  for (int i = 0; i < 12; ++i) w[i] = wcl[(size_t)n*1920 + o*192 + d*12 + i];
  for (int b = bh*32; b < bh*32+32; ++b) {
    float acc = 0.f;
    #pragma unroll
    for (int i = 0; i < 12; ++i) acc = fmaf(w[i], u2l[b][i], acc);
    uhat2[((size_t)b*784 + n)*160 + od] = f2bf(acc);
  }
}

// ---------------- class routing: wave-local pass, no barriers in main loop ----------------
template<int MODE>
__global__ __launch_bounds__(256) void cls_pass(const unsigned short* __restrict__ uh2b,
                                                const float* __restrict__ vprev,
                                                float* __restrict__ b2l,
                                                float* __restrict__ cpart) {
  const int b = blockIdx.x, sl = blockIdx.y;   // sl 0..6
  const int tid = threadIdx.x, lane = tid & 63, wv = tid >> 6;
  const int nl = lane >> 4, d = lane & 15;
  float v[10];
  if (MODE != 0) {
    #pragma unroll
    for (int o = 0; o < 10; ++o) v[o] = vprev[b*160 + o*16 + d];
  }
  float sacc[10];
  #pragma unroll
  for (int o = 0; o < 10; ++o) sacc[o] = 0.f;
  for (int step = 0; step < 7; ++step) {
    const int n = sl*112 + step*16 + wv*4 + nl;
    const unsigned short* up = uh2b + ((size_t)b*784 + n)*160 + d;
    float u[10];
    #pragma unroll
    for (int o = 0; o < 10; ++o) u[o] = bf2f(up[o*16]);
    if (MODE == 0) {
      #pragma unroll
      for (int o = 0; o < 10; ++o) sacc[o] += u[o];
    } else {
      float bb[10];
      #pragma unroll
      for (int o = 0; o < 10; ++o) {
        float t = v[o]*u[o];
        #pragma unroll
        for (int off = 8; off; off >>= 1) t += __shfl_xor(t, off, 16);
        bb[o] = t;
      }
      if (MODE == 2) {
        #pragma unroll
        for (int o = 0; o < 10; ++o) bb[o] += b2l[((size_t)b*784 + n)*10 + o];
      }
      if (MODE == 1 && d < 10) b2l[((size_t)b*784 + n)*10 + d] = bb[d];
      float mx = bb[0];
      #pragma unroll
      for (int o = 1; o < 10; ++o) mx = fmaxf(mx, bb[o]);
      float es = 0.f;
      #pragma unroll
      for (int o = 0; o < 10; ++o) { bb[o] = __expf(bb[o]-mx); es += bb[o]; }
      float inv = 1.f/es;
      #pragma unroll
      for (int o = 0; o < 10; ++o) sacc[o] = fmaf(bb[o]*inv, u[o], sacc[o]);
    }
  }
  #pragma unroll
  for (int o = 0; o < 10; ++o) {
    sacc[o] += __shfl_xor(sacc[o], 16, 64);
    sacc[o] += __shfl_xor(sacc[o], 32, 64);
  }
  __shared__ float red[4][160];
  if (lane < 16) {
    #pragma unroll
    for (int o = 0; o < 10; ++o) red[wv][o*16 + d] = sacc[o];
  }
  __syncthreads();
  if (tid < 160) {
    float s = red[0][tid] + red[1][tid] + red[2][tid] + red[3][tid];
    cpart[((size_t)b*7 + sl)*160 + tid] = s;
  }
}

__global__ __launch_bounds__(160) void cls_finish(const float* __restrict__ cpart,
                                                  float* __restrict__ vout, float fac) {
  int b = blockIdx.x, od = threadIdx.x;
  float s = 0.f;
  #pragma unroll
  for (int sl = 0; sl < 7; ++sl) s += cpart[((size_t)b*7 + sl)*160 + od];
  s *= fac;
  float nrm = s*s;
  #pragma unroll
  for (int off = 8; off; off >>= 1) nrm += __shfl_xor(nrm, off, 16);
  float sc = nrm / ((1.f + nrm)*sqrtf(nrm + 1e-6f));
  vout[(size_t)b*160 + od] = s*sc;
}

// ---------------- host launch ----------------
extern "C" void kernel_launch(void* const* d_in, const int* in_sizes, int n_in,
                              void* d_out, int out_size, void* d_ws, size_t ws_size,
                              hipStream_t stream) {
  const float* images = (const float*)d_in[0];
  const float* w1  = (const float*)d_in[1];
  const float* g1  = (const float*)d_in[2];
  const float* b1  = (const float*)d_in[3];
  const float* w2  = (const float*)d_in[4];
  const float* g2  = (const float*)d_in[5];
  const float* b2  = (const float*)d_in[6];
  const float* w3  = (const float*)d_in[7];
  const float* g3  = (const float*)d_in[8];
  const float* b3  = (const float*)d_in[9];
  const float* wp  = (const float*)d_in[10];
  const float* bp  = (const float*)d_in[11];
  const float* wcc = (const float*)d_in[12];
  const float* wcl = (const float*)d_in[13];
  float* out = (float*)d_out;
  float* ws  = (float*)d_ws;

  // persistent regions (float offsets)
  float* t1    = ws + 0;            // 3,145,728
  float* t2    = ws + 3145728;      // 1,572,864
  float* t3    = ws + 4718592;      // 3,145,728
  float* pc    = ws + 7864320;      //   602,112
  float* uu    = ws + 8466432;      // 5,419,008
  float* u2b   = ws + 13885440;     //   602,112
  unsigned short* uh2b = (unsigned short*)(ws + 14487552);  // 8,028,160 ushorts
  float* b2l   = ws + 22515712;     //   501,760
  float* scrC  = ws + 23017472;     //   501,760 (BN stats during convs, cpart during class)
  float* v2    = ws + 23519232;     //    10,240
  float* spart = ws + 23529472;     //     3,072
  float* ssc1  = ws + 23532544;     //        96
  float* ssc2  = ws + 23532640;     //       192
  float* ssc3  = ws + 23532832;     //       384
  float* U     = ws + 23533312;     // arena, 10,838,016 f32 (conv transients)
  __hip_bfloat16* uhc = (__hip_bfloat16*)(ws + 34371328);   // 43,352,064 bf16 (one 32-img chunk)

  // split/reordered weights live in dead `uu` region (dead until uu_gather)
  unsigned short* wh2 = (unsigned short*)(uu + 0);
  unsigned short* wl2 = (unsigned short*)(uu + 20736);
  unsigned short* wh3 = (unsigned short*)(uu + 41472);
  unsigned short* wl3 = (unsigned short*)(uu + 124416);
  unsigned short* whp = (unsigned short*)(uu + 207360);
  unsigned short* wlp = (unsigned short*)(uu + 373248);

  // phase transients in the U arena
  unsigned short* x2h = (unsigned short*)(U + 0);
  unsigned short* x2l = (unsigned short*)(U + 1775616);
  float*          part2 = U + 3551232;                    // 3x96x16384
  unsigned short* x3h = (unsigned short*)(U + 0);
  unsigned short* x3l = (unsigned short*)(U + 995328);
  unsigned short* xph = (unsigned short*)(U + 0);
  unsigned short* xpl = (unsigned short*)(U + 1572864);
  float*          partp = U + 3145728;                    // 8x192x3136

  const int B = 64;

  // merged weight splits
  split_w_all<<<2106,256,0,stream>>>(w2, w3, wp, wh2, wl2, wh3, wl3, whp, wlp);

  // conv1 + BN1 stats
  conv1_fused<<<2048,192,0,stream>>>(images, w1, t1);
  bn_partial<48,1024,8><<<48*8,256,0,stream>>>(t1, spart, B);
  bn_final<48,8><<<1,64,0,stream>>>(spart, g1, b1, ssc1, 65536);

  // conv2: BN1+ReLU+split (with halos), MFMA split-K=3, reduce+stats
  bn_split_nhwc<48,32,32,1><<<64*34,256,0,stream>>>(t1, ssc1, x2h, x2l);
  conv_mfma<48,34,34,16,16,2,3><<<dim3(2,128,3),256,0,stream>>>(x2h, x2l, wh2, wl2, part2, 96, B);
  splitk_reduce<96,256,3,false,true><<<6144,256,0,stream>>>(part2, nullptr, t2, scrC, B);
  bn_final<96,64><<<1,128,0,stream>>>(scrC, g2, b2, ssc2, 16384);

  // conv3: direct NCHW write (split-K=1), stats via bn_partial
  bn_split_nhwc<96,16,16,1><<<64*18,256,0,stream>>>(t2, ssc2, x3h, x3l);
  conv_mfma<96,18,18,16,16,1,1><<<dim3(3,128,1),256,0,stream>>>(x3h, x3l, wh3, wl3, t3, 192, B);
  bn_partial<192,256,8><<<192*8,256,0,stream>>>(t3, spart, B);
  bn_final<192,8><<<1,192,0,stream>>>(spart, g3, b3, ssc3, 16384);

  // primary caps conv + bias, then squash
  bn_split_nhwc<192,16,16,0><<<64*16,256,0,stream>>>(t3, ssc3, xph, xpl);
  conv_mfma<192,16,16,7,7,2,8><<<dim3(3,25,8),256,0,stream>>>(xph, xpl, whp, wlp, partp, 192, B);
  splitk_reduce<192,49,8,true,false><<<2352,256,0,stream>>>(partp, bp, pc, nullptr, B);
  squash_pc<<<196,256,0,stream>>>(pc, 50176);

  // uu gather
  uu_gather<<<21168,256,0,stream>>>(pc, uu, B);
  // ConvCaps einsum (wide stores) + register-stash fused routing, 2 chunks of 32 images
  for (int cb = 0; cb < 2; ++cb) {
    cc_einsum3<<<dim3(144,25),192,0,stream>>>(uu, wcc, uhc, cb*1568, 1568);
    cc_route<<<1568,384,0,stream>>>(uhc, u2b, cb*1568);
  }
  // Class caps einsum (bf16) + wave-local routing
  class_einsum<<<784,320,0,stream>>>(u2b, wcl, uh2b, B);
  cls_pass<0><<<dim3(64,7),256,0,stream>>>(uh2b, v2, b2l, scrC);
  cls_finish<<<64,160,0,stream>>>(scrC, v2, 0.1f);
  cls_pass<1><<<dim3(64,7),256,0,stream>>>(uh2b, v2, b2l, scrC);
  cls_finish<<<64,160,0,stream>>>(scrC, v2, 1.0f);
  cls_pass<2><<<dim3(64,7),256,0,stream>>>(uh2b, v2, b2l, scrC);
  cls_finish<<<64,160,0,stream>>>(scrC, out, 1.0f);
  (void)in_sizes; (void)n_in; (void)out_size; (void)ws_size;
}

// Round 14
// 380.736 us; speedup vs baseline: 1.6465x; 1.6465x over previous
//
#include <hip/hip_runtime.h>
#include <hip/hip_bf16.h>

typedef __attribute__((ext_vector_type(4))) short short4v;
typedef __attribute__((ext_vector_type(8))) short short8v;
typedef __attribute__((ext_vector_type(16))) float f32x16;

union frag8 { short8v v8; struct { short4v lo, hi; } p; };

__device__ __forceinline__ unsigned short f2bf(float v) {
  unsigned u = __float_as_uint(v);
  unsigned r = u + 0x7fffu + ((u >> 16) & 1u);
  return (unsigned short)(r >> 16);
}
__device__ __forceinline__ float bf2f(unsigned short h) {
  return __uint_as_float(((unsigned)h) << 16);
}

// ---------------- conv1: one block per (b,h), LDS input slab, weights in regs ----------------
__global__ __launch_bounds__(192) void conv1_fused(const float* __restrict__ images,
                                                   const float* __restrict__ w1,
                                                   float* __restrict__ out) {
  int b = blockIdx.x >> 5, h = blockIdx.x & 31;
  __shared__ __align__(16) float lin[3][3][36];
  int tid = threadIdx.x;
  for (int e = tid; e < 324; e += 192) {
    int ci = e / 108, rem = e % 108, ki = rem / 36, wi = rem % 36;
    int row = h + ki - 1, col = wi - 1;
    float v = 0.f;
    if (row >= 0 && row < 32 && col >= 0 && col < 32)
      v = images[((size_t)(b*3 + ci)*32 + row)*32 + col];
    lin[ci][ki][wi] = v;
  }
  int co = tid >> 2, ws = tid & 3;
  float wr[27];
  #pragma unroll
  for (int j = 0; j < 27; ++j) wr[j] = w1[co*27 + j];
  __syncthreads();
  float o[8];
  #pragma unroll
  for (int j = 0; j < 8; ++j) o[j] = 0.f;
  #pragma unroll
  for (int ci = 0; ci < 3; ++ci)
    #pragma unroll
    for (int ki = 0; ki < 3; ++ki) {
      float4 q0 = *(const float4*)&lin[ci][ki][ws*8];
      float4 q1 = *(const float4*)&lin[ci][ki][ws*8+4];
      float4 q2 = *(const float4*)&lin[ci][ki][ws*8+8];
      float r[12] = {q0.x,q0.y,q0.z,q0.w,q1.x,q1.y,q1.z,q1.w,q2.x,q2.y,q2.z,q2.w};
      #pragma unroll
      for (int kj = 0; kj < 3; ++kj) {
        float wv = wr[(ci*3+ki)*3+kj];
        #pragma unroll
        for (int j = 0; j < 8; ++j) o[j] = fmaf(r[j+kj], wv, o[j]);
      }
    }
  float* dst = out + (((size_t)(b*48+co)*32 + h)*32 + ws*8);
  *(float4*)dst       = make_float4(o[0],o[1],o[2],o[3]);
  *(float4*)(dst + 4) = make_float4(o[4],o[5],o[6],o[7]);
}

// ---------------- merged weight split+reorder for conv2/conv3/primary ----------------
__device__ __forceinline__ void split_one(const float* w, unsigned short* wh,
                                          unsigned short* wl, int CI, int i) {
  int K = CI*9;
  int co = i / K, rem = i % K, tap = rem / CI, ci = rem % CI;
  float v = w[(co*CI + ci)*9 + tap];
  unsigned short h = f2bf(v);
  wh[i] = h;
  wl[i] = f2bf(v - bf2f(h));
}
__global__ void split_w_all(const float* __restrict__ w2, const float* __restrict__ w3,
                            const float* __restrict__ wp,
                            unsigned short* wh2, unsigned short* wl2,
                            unsigned short* wh3, unsigned short* wl3,
                            unsigned short* whp, unsigned short* wlp) {
  int i = blockIdx.x*256 + threadIdx.x;
  if (i < 41472) split_one(w2, wh2, wl2, 48, i);
  else if (i < 207360) split_one(w3, wh3, wl3, 96, i - 41472);
  else if (i < 539136) split_one(wp, whp, wlp, 192, i - 207360);
}

// ---------------- BN affine + ReLU + split to padded NHWC bf16 hi/lo (writes halos) ----------------
template<int C,int H,int W,int P>
__global__ void bn_split_nhwc(const float* __restrict__ in, const float* __restrict__ sc,
                              unsigned short* __restrict__ xh, unsigned short* __restrict__ xl) {
  constexpr int HP = H + 2*P, WP = W + 2*P;
  int b = blockIdx.x / HP, hp = blockIdx.x % HP;
  int h = hp - P;
  for (int e = threadIdx.x; e < WP*C; e += 256) {
    int wp = e / C, c = e % C;
    int w = wp - P;
    float v = 0.f;
    if (h >= 0 && h < H && w >= 0 && w < W) {
      v = in[((size_t)(b*C + c)*H + h)*W + w];
      v = fmaf(v, sc[c*2], sc[c*2+1]);
      v = v > 0.f ? v : 0.f;
    }
    unsigned short hh = f2bf(v);
    size_t o = ((size_t)(b*HP + hp)*WP + wp)*C + c;
    xh[o] = hh;
    xl[o] = f2bf(v - bf2f(hh));
  }
}

// ---------------- MFMA implicit-GEMM conv; SPLITK==1 writes NCHW directly ----------------
template<int CI,int HIP,int WIP,int HO,int WO,int STR,int SPLITK>
__global__ __launch_bounds__(256,4) void conv_mfma(
    const unsigned short* __restrict__ xh, const unsigned short* __restrict__ xl,
    const unsigned short* __restrict__ wh, const unsigned short* __restrict__ wl,
    float* __restrict__ part, int CO, int B) {
  constexpr int K = CI*9, NSP = HO*WO, KCH = K/SPLITK, LDA = 36;
  const int NTOT = B*NSP;
  const int m0 = blockIdx.x*64, n0 = blockIdx.y*128, ks = blockIdx.z;
  __shared__ unsigned short Ah[64*LDA], Al[64*LDA], Bh[128*LDA], Bl[128*LDA];
  const int tid = threadIdx.x, lane = tid & 63, wid = tid >> 6;
  const int wm = wid >> 1, wn = wid & 1;
  const int arow = tid >> 2, ak0 = (tid & 3)*8;
  const bool aok = (m0 + arow) < CO;
  const size_t abase = (size_t)(m0 + arow)*K;
  int brow[2], bk0[2];
  size_t bbase[2];
  #pragma unroll
  for (int i = 0; i < 2; ++i) {
    int e = tid + i*256;
    brow[i] = e >> 2; bk0[i] = (e & 3)*8;
    int nn = n0 + brow[i]; if (nn > NTOT-1) nn = NTOT-1;
    int bb = nn / NSP, sp = nn % NSP;
    int ho = sp / WO, wo = sp % WO;
    bbase[i] = ((size_t)bb*HIP + ho*STR)*WIP + wo*STR;
  }
  f32x16 acc0 = (f32x16)0.f, acc1 = (f32x16)0.f;
  const int kBeg = ks*KCH, kEnd = kBeg + KCH;
  for (int kc = kBeg; kc < kEnd; kc += 32) {
    const int kLim = (kEnd - kc) < 32 ? (kEnd - kc) : 32;
    {
      frag8 vh, vl;
      vh.v8 = (short8v)(short)0; vl.v8 = (short8v)(short)0;
      if (aok && ak0 < kLim) {
        size_t off = abase + kc + ak0;
        vh.v8 = *(const short8v*)(wh + off);
        vl.v8 = *(const short8v*)(wl + off);
      }
      int lo_ = arow*LDA + ak0;
      *(short4v*)(Ah + lo_) = vh.p.lo; *(short4v*)(Ah + lo_ + 4) = vh.p.hi;
      *(short4v*)(Al + lo_) = vl.p.lo; *(short4v*)(Al + lo_ + 4) = vl.p.hi;
    }
    #pragma unroll
    for (int i = 0; i < 2; ++i) {
      frag8 vh, vl;
      vh.v8 = (short8v)(short)0; vl.v8 = (short8v)(short)0;
      if (bk0[i] < kLim) {
        int kg = kc + bk0[i];
        int tap = kg / CI, ci0 = kg - tap*CI;
        int dh = tap / 3, dw = tap - dh*3;
        size_t off = (bbase[i] + (size_t)dh*WIP + dw)*CI + ci0;
        vh.v8 = *(const short8v*)(xh + off);
        vl.v8 = *(const short8v*)(xl + off);
      }
      int lo_ = brow[i]*LDA + bk0[i];
      *(short4v*)(Bh + lo_) = vh.p.lo; *(short4v*)(Bh + lo_ + 4) = vh.p.hi;
      *(short4v*)(Bl + lo_) = vl.p.lo; *(short4v*)(Bl + lo_ + 4) = vl.p.hi;
    }
    __syncthreads();
    #pragma unroll
    for (int kst = 0; kst < 2; ++kst) {
      const int kb = kst*16 + 8*(lane >> 5);
      const int ar = wm*32 + (lane & 31);
      frag8 ah, al;
      { int o = ar*LDA + kb;
        ah.p.lo = *(const short4v*)(Ah + o); ah.p.hi = *(const short4v*)(Ah + o + 4);
        al.p.lo = *(const short4v*)(Al + o); al.p.hi = *(const short4v*)(Al + o + 4); }
      const int br = wn*64 + (lane & 31);
      frag8 bh0, bl0, bh1, bl1;
      { int o = br*LDA + kb;
        bh0.p.lo = *(const short4v*)(Bh + o); bh0.p.hi = *(const short4v*)(Bh + o + 4);
        bl0.p.lo = *(const short4v*)(Bl + o); bl0.p.hi = *(const short4v*)(Bl + o + 4); }
      { int o = (br+32)*LDA + kb;
        bh1.p.lo = *(const short4v*)(Bh + o); bh1.p.hi = *(const short4v*)(Bh + o + 4);
        bl1.p.lo = *(const short4v*)(Bl + o); bl1.p.hi = *(const short4v*)(Bl + o + 4); }
      acc0 = __builtin_amdgcn_mfma_f32_32x32x16_bf16(ah.v8, bh0.v8, acc0, 0, 0, 0);
      acc0 = __builtin_amdgcn_mfma_f32_32x32x16_bf16(ah.v8, bl0.v8, acc0, 0, 0, 0);
      acc0 = __builtin_amdgcn_mfma_f32_32x32x16_bf16(al.v8, bh0.v8, acc0, 0, 0, 0);
      acc1 = __builtin_amdgcn_mfma_f32_32x32x16_bf16(ah.v8, bh1.v8, acc1, 0, 0, 0);
      acc1 = __builtin_amdgcn_mfma_f32_32x32x16_bf16(ah.v8, bl1.v8, acc1, 0, 0, 0);
      acc1 = __builtin_amdgcn_mfma_f32_32x32x16_bf16(al.v8, bh1.v8, acc1, 0, 0, 0);
    }
    __syncthreads();
  }
  #pragma unroll
  for (int ns = 0; ns < 2; ++ns) {
    f32x16 a = ns ? acc1 : acc0;
    #pragma unroll
    for (int r = 0; r < 16; ++r) {
      int row = (r & 3) + 8*(r >> 2) + 4*(lane >> 5);
      int m = m0 + wm*32 + row;
      int n = n0 + wn*64 + ns*32 + (lane & 31);
      if (m < CO && n < NTOT) {
        if (SPLITK == 1) {
          int b = n / NSP, sp = n % NSP;
          part[((size_t)b*CO + m)*NSP + sp] = a[r];
        } else {
          part[((size_t)ks*CO + m)*NTOT + n] = a[r];
        }
      }
    }
  }
}

// ---------------- split-K reduce (+bias, + optional fused BN partial stats) ----------------
template<int CO,int NSP,int SPLITK,bool BIAS,bool STATS>
__global__ void splitk_reduce(const float* __restrict__ part, const float* __restrict__ bias,
                              float* __restrict__ out, float* __restrict__ stats, int B) {
  const int NTOT = B*NSP;
  int i = blockIdx.x*256 + threadIdx.x;
  bool valid = i < CO*NTOT;
  float s = 0.f;
  if (valid) {
    int co = i / NTOT, n = i % NTOT;
    #pragma unroll
    for (int ks = 0; ks < SPLITK; ++ks) s += part[(size_t)(ks*CO + co)*NTOT + n];
    if (BIAS) s += bias[co];
    int b = n / NSP, sp = n % NSP;
    out[((size_t)b*CO + co)*NSP + sp] = s;
  }
  if (STATS) {
    float sum = valid ? s : 0.f, sq = valid ? s*s : 0.f;
    #pragma unroll
    for (int off = 32; off; off >>= 1) {
      sum += __shfl_down(sum, off, 64);
      sq  += __shfl_down(sq,  off, 64);
    }
    __shared__ float ls[2][4];
    int lane = threadIdx.x & 63, wv = threadIdx.x >> 6;
    if (lane == 0) { ls[0][wv] = sum; ls[1][wv] = sq; }
    __syncthreads();
    if (threadIdx.x == 0) {
      float S = 0.f, Q = 0.f;
      #pragma unroll
      for (int j = 0; j < 4; ++j) { S += ls[0][j]; Q += ls[1][j]; }
      int bpc = NTOT/256;
      int co = blockIdx.x / bpc, slice = blockIdx.x % bpc;
      stats[(co*bpc + slice)*2 + 0] = S;
      stats[(co*bpc + slice)*2 + 1] = Q;
    }
  }
}

// ---------------- BN stats ----------------
template<int C,int HW,int SLICES>
__global__ void bn_partial(const float* __restrict__ x, float* __restrict__ part, int B) {
  int c = blockIdx.x / SLICES, s = blockIdx.x % SLICES;
  int bpp = B / SLICES;
  float sum = 0.f, sq = 0.f;
  for (int b = s*bpp; b < (s+1)*bpp; ++b) {
    const float* p = x + ((size_t)b*C + c)*HW;
    for (int i = threadIdx.x; i < HW; i += blockDim.x) {
      float v = p[i]; sum += v; sq += v*v;
    }
  }
  #pragma unroll
  for (int off = 32; off; off >>= 1) {
    sum += __shfl_down(sum, off, 64);
    sq  += __shfl_down(sq,  off, 64);
  }
  __shared__ float ls[2][4];
  int lane = threadIdx.x & 63, wv = threadIdx.x >> 6;
  if (lane == 0) { ls[0][wv] = sum; ls[1][wv] = sq; }
  __syncthreads();
  if (threadIdx.x == 0) {
    float S = 0.f, Q = 0.f;
    #pragma unroll
    for (int i = 0; i < 4; ++i) { S += ls[0][i]; Q += ls[1][i]; }
    part[(c*SLICES+s)*2+0] = S; part[(c*SLICES+s)*2+1] = Q;
  }
}

template<int C,int SLICES>
__global__ void bn_final(const float* __restrict__ part, const float* __restrict__ g,
                         const float* __restrict__ bta, float* __restrict__ sc, int NHW) {
  int c = blockIdx.x*blockDim.x + threadIdx.x;
  if (c >= C) return;
  float S = 0.f, Q = 0.f;
  for (int s = 0; s < SLICES; ++s) { S += part[(c*SLICES+s)*2]; Q += part[(c*SLICES+s)*2+1]; }
  float m = S / NHW, v = Q / NHW - m*m;
  float inv = rsqrtf(v + 1e-5f);
  float a = g[c] * inv;
  sc[c*2] = a; sc[c*2+1] = bta[c] - m*a;
}

// ---------------- squash primary caps in place ----------------
__global__ void squash_pc(float* __restrict__ pc, int ncaps) {
  int i = blockIdx.x*blockDim.x + threadIdx.x;
  if (i >= ncaps) return;
  float* p = pc + (size_t)i*12;
  float v[12]; float s = 0.f;
  #pragma unroll
  for (int d = 0; d < 12; ++d) { v[d] = p[d]; s += v[d]*v[d]; }
  float sc = s / ((1.f + s)*sqrtf(s + 1e-6f));
  #pragma unroll
  for (int d = 0; d < 12; ++d) p[d] = v[d]*sc;
}

// ---------------- uu gather ----------------
__global__ void uu_gather(const float* __restrict__ sq, float* __restrict__ uu, int B) {
  int idx = blockIdx.x*blockDim.x + threadIdx.x;
  int total = B*49*144*12;
  if (idx >= total) return;
  int ii = idx % 12; int t0 = idx / 12;
  int kk = t0 % 144; t0 /= 144;
  int tt = t0 % 49;  int b = t0 / 49;
  int f = tt*1728 + kk*12 + ii;
  int c = f / 441; int r = f - c*441;
  int k = r / 49;  int sp = r - k*49;
  int y = sp / 7, x = sp - y*7;
  int iy = y + k/3 - 1, ix = x + (k%3) - 1;
  float val = 0.f;
  if (iy >= 0 && iy < 7 && ix >= 0 && ix < 7)
    val = sq[((size_t)(b*192 + c)*7 + iy)*7 + ix];
  uu[idx] = val;
}

// ---------------- ConvCaps einsum: 4 o's + 16 m's per thread, ushort4 stores ----------------
__global__ __launch_bounds__(192) void cc_einsum3(const float* __restrict__ uu,
                                                  const float* __restrict__ wcc,
                                                  __hip_bfloat16* __restrict__ uhat,
                                                  int row0, int nrows) {
  const int k  = blockIdx.x;
  const int m0 = blockIdx.y * 64;
  const int tid = threadIdx.x;
  const int m4 = tid / 48, oq = tid % 48;
  float wr[4][12];
  #pragma unroll
  for (int c = 0; c < 4; ++c) {
    const float4* wp4 = (const float4*)(wcc + ((size_t)k*192 + oq*4 + c)*12);
    float4 a = wp4[0], b = wp4[1], d = wp4[2];
    wr[c][0]=a.x; wr[c][1]=a.y; wr[c][2]=a.z; wr[c][3]=a.w;
    wr[c][4]=b.x; wr[c][5]=b.y; wr[c][6]=b.z; wr[c][7]=b.w;
    wr[c][8]=d.x; wr[c][9]=d.y; wr[c][10]=d.z; wr[c][11]=d.w;
  }
  int mmax = nrows - m0; if (mmax > 64) mmax = 64;
  #pragma unroll 4
  for (int mi = 0; mi < 16; ++mi) {
    int m = m4*16 + mi;
    if (m >= mmax) break;
    const float4* ar = (const float4*)(uu + ((size_t)(row0+m0+m)*144 + k)*12);
    float4 a0 = ar[0], a1 = ar[1], a2 = ar[2];
    float af[12] = {a0.x,a0.y,a0.z,a0.w,a1.x,a1.y,a1.z,a1.w,a2.x,a2.y,a2.z,a2.w};
    ushort4 pkt;
    unsigned short* pp = (unsigned short*)&pkt;
    #pragma unroll
    for (int c = 0; c < 4; ++c) {
      float acc = 0.f;
      #pragma unroll
      for (int i = 0; i < 12; ++i) acc = fmaf(wr[c][i], af[i], acc);
      pp[c] = f2bf(acc);
    }
    unsigned short* up = (unsigned short*)uhat + ((size_t)(m0+m)*144 + k)*192 + oq*4;
    *(ushort4*)up = pkt;
  }
}

// ---------------- ConvCaps routing: small register stash (24 groups), fused 3-pass -----------
// 384 threads = 24 groups x 16 lanes. lane=(g,oc); group g owns k = g+24j, j=0..5.
// launch_bounds(384,4): VGPR cap 128, compiler uses ~64, NO SPILL (round-11-proven).
__global__ __launch_bounds__(384,4) void cc_route(const __hip_bfloat16* __restrict__ uhat,
                                                  float* __restrict__ u2, int rowOff) {
  const int row = blockIdx.x;
  const unsigned short* __restrict__ uh = (const unsigned short*)uhat + (size_t)row*27648;
  __shared__ float red[6][192];
  __shared__ float sraw[192];
  __shared__ float vsh[192];
  const int tid = threadIdx.x, lane = tid & 63, wv = tid >> 6;
  const int g = tid >> 4, oc = tid & 15;
  uint2 st[6][3];
  float blog[6];
  #pragma unroll
  for (int j = 0; j < 6; ++j) blog[j] = 0.f;
  float sacc[12];

  // ---- pass 0: load + stash + uniform-c sum
  #pragma unroll
  for (int d = 0; d < 12; ++d) sacc[d] = 0.f;
  #pragma unroll
  for (int j = 0; j < 6; ++j) {
    const unsigned short* up = uh + (g + 24*j)*192 + oc*12;
    uint2 q0 = *(const uint2*)up;
    uint2 q1 = *(const uint2*)(up + 4);
    uint2 q2 = *(const uint2*)(up + 8);
    st[j][0] = q0; st[j][1] = q1; st[j][2] = q2;
    sacc[0] += bf2f((unsigned short)(q0.x & 0xffff)); sacc[1] += bf2f((unsigned short)(q0.x >> 16));
    sacc[2] += bf2f((unsigned short)(q0.y & 0xffff)); sacc[3] += bf2f((unsigned short)(q0.y >> 16));
    sacc[4] += bf2f((unsigned short)(q1.x & 0xffff)); sacc[5] += bf2f((unsigned short)(q1.x >> 16));
    sacc[6] += bf2f((unsigned short)(q1.y & 0xffff)); sacc[7] += bf2f((unsigned short)(q1.y >> 16));
    sacc[8] += bf2f((unsigned short)(q2.x & 0xffff)); sacc[9] += bf2f((unsigned short)(q2.x >> 16));
    sacc[10] += bf2f((unsigned short)(q2.y & 0xffff)); sacc[11] += bf2f((unsigned short)(q2.y >> 16));
  }
  #pragma unroll
  for (int d = 0; d < 12; ++d) {
    sacc[d] += __shfl_xor(sacc[d], 16, 64);
    sacc[d] += __shfl_xor(sacc[d], 32, 64);
  }
  if (lane < 16) {
    #pragma unroll
    for (int d = 0; d < 12; ++d) red[wv][oc*12 + d] = sacc[d];
  }
  __syncthreads();
  if (tid < 192) {
    float s = (red[0][tid] + red[1][tid] + red[2][tid]
             + red[3][tid] + red[4][tid] + red[5][tid]) * 0.0625f;
    sraw[tid] = s;
  }
  __syncthreads();
  if (tid < 192) {
    int qc = tid / 12;
    float nrm = 0.f;
    #pragma unroll
    for (int d = 0; d < 12; ++d) { float v = sraw[qc*12 + d]; nrm += v*v; }
    float sc = nrm / ((1.f + nrm)*sqrtf(nrm + 1e-6f));
    vsh[tid] = sraw[tid]*sc;
  }
  __syncthreads();

  // ---- passes 1,2: all-register data
  #pragma unroll
  for (int r = 1; r < 3; ++r) {
    float vq[12];
    #pragma unroll
    for (int d = 0; d < 12; ++d) vq[d] = vsh[oc*12 + d];
    #pragma unroll
    for (int d = 0; d < 12; ++d) sacc[d] = 0.f;
    #pragma unroll
    for (int j = 0; j < 6; ++j) {
      uint2 q0 = st[j][0], q1 = st[j][1], q2 = st[j][2];
      float uf[12];
      uf[0] = bf2f((unsigned short)(q0.x & 0xffff)); uf[1] = bf2f((unsigned short)(q0.x >> 16));
      uf[2] = bf2f((unsigned short)(q0.y & 0xffff)); uf[3] = bf2f((unsigned short)(q0.y >> 16));
      uf[4] = bf2f((unsigned short)(q1.x & 0xffff)); uf[5] = bf2f((unsigned short)(q1.x >> 16));
      uf[6] = bf2f((unsigned short)(q1.y & 0xffff)); uf[7] = bf2f((unsigned short)(q1.y >> 16));
      uf[8] = bf2f((unsigned short)(q2.x & 0xffff)); uf[9] = bf2f((unsigned short)(q2.x >> 16));
      uf[10] = bf2f((unsigned short)(q2.y & 0xffff)); uf[11] = bf2f((unsigned short)(q2.y >> 16));
      float dot = 0.f;
      #pragma unroll
      for (int d = 0; d < 12; ++d) dot = fmaf(vq[d], uf[d], dot);
      blog[j] += dot;
      float mx = blog[j];
      #pragma unroll
      for (int off = 1; off < 16; off <<= 1) mx = fmaxf(mx, __shfl_xor(mx, off, 16));
      float e = __expf(blog[j] - mx);
      float es = e;
      #pragma unroll
      for (int off = 1; off < 16; off <<= 1) es += __shfl_xor(es, off, 16);
      float c = e / es;
      #pragma unroll
      for (int d = 0; d < 12; ++d) sacc[d] = fmaf(c, uf[d], sacc[d]);
    }
    #pragma unroll
    for (int d = 0; d < 12; ++d) {
      sacc[d] += __shfl_xor(sacc[d], 16, 64);
      sacc[d] += __shfl_xor(sacc[d], 32, 64);
    }
    if (lane < 16) {
      #pragma unroll
      for (int d = 0; d < 12; ++d) red[wv][oc*12 + d] = sacc[d];
    }
    __syncthreads();
    if (tid < 192) {
      sraw[tid] = red[0][tid] + red[1][tid] + red[2][tid]
                + red[3][tid] + red[4][tid] + red[5][tid];
    }
    __syncthreads();
    if (tid < 192) {
      int qc = tid / 12;
      float nrm = 0.f;
      #pragma unroll
      for (int d = 0; d < 12; ++d) { float v = sraw[qc*12 + d]; nrm += v*v; }
      float sc = nrm / ((1.f + nrm)*sqrtf(nrm + 1e-6f));
      vsh[tid] = sraw[tid]*sc;
    }
    __syncthreads();
  }
  if (tid < 192) u2[((size_t)(rowOff + row))*192 + tid] = vsh[tid];
}

// ---------------- Class caps einsum (bf16 output) ----------------
__global__ void class_einsum(const float* __restrict__ u2, const float* __restrict__ wcl,
                             unsigned short* __restrict__ uhat2, int B) {
  int n = blockIdx.x;
  __shared__ float u2l[64][12];
  int tid = threadIdx.x;
  for (int e = tid; e < 64*12; e += 320) {
    int b = e / 12, i = e % 12;
    u2l[b][i] = u2[(size_t)b*9408 + n*12 + i];
  }
  __syncthreads();
  int od = tid % 160, bh = tid / 160;
  int o = od >> 4, d = od & 15;
  float w[12];
  #pragma unroll
  for (int i = 0; i < 12; ++i) w[i] = wcl[(size_t)n*1920 + o*192 + d*12 + i];
  for (int b = bh*32; b < bh*32+32; ++b) {
    float acc = 0.f;
    #pragma unroll
    for (int i = 0; i < 12; ++i) acc = fmaf(w[i], u2l[b][i], acc);
    uhat2[((size_t)b*784 + n)*160 + od] = f2bf(acc);
  }
}

// ---------------- class routing: wave-local pass, no barriers in main loop ----------------
template<int MODE>
__global__ __launch_bounds__(256) void cls_pass(const unsigned short* __restrict__ uh2b,
                                                const float* __restrict__ vprev,
                                                float* __restrict__ b2l,
                                                float* __restrict__ cpart) {
  const int b = blockIdx.x, sl = blockIdx.y;   // sl 0..6
  const int tid = threadIdx.x, lane = tid & 63, wv = tid >> 6;
  const int nl = lane >> 4, d = lane & 15;
  float v[10];
  if (MODE != 0) {
    #pragma unroll
    for (int o = 0; o < 10; ++o) v[o] = vprev[b*160 + o*16 + d];
  }
  float sacc[10];
  #pragma unroll
  for (int o = 0; o < 10; ++o) sacc[o] = 0.f;
  for (int step = 0; step < 7; ++step) {
    const int n = sl*112 + step*16 + wv*4 + nl;
    const unsigned short* up = uh2b + ((size_t)b*784 + n)*160 + d;
    float u[10];
    #pragma unroll
    for (int o = 0; o < 10; ++o) u[o] = bf2f(up[o*16]);
    if (MODE == 0) {
      #pragma unroll
      for (int o = 0; o < 10; ++o) sacc[o] += u[o];
    } else {
      float bb[10];
      #pragma unroll
      for (int o = 0; o < 10; ++o) {
        float t = v[o]*u[o];
        #pragma unroll
        for (int off = 8; off; off >>= 1) t += __shfl_xor(t, off, 16);
        bb[o] = t;
      }
      if (MODE == 2) {
        #pragma unroll
        for (int o = 0; o < 10; ++o) bb[o] += b2l[((size_t)b*784 + n)*10 + o];
      }
      if (MODE == 1 && d < 10) b2l[((size_t)b*784 + n)*10 + d] = bb[d];
      float mx = bb[0];
      #pragma unroll
      for (int o = 1; o < 10; ++o) mx = fmaxf(mx, bb[o]);
      float es = 0.f;
      #pragma unroll
      for (int o = 0; o < 10; ++o) { bb[o] = __expf(bb[o]-mx); es += bb[o]; }
      float inv = 1.f/es;
      #pragma unroll
      for (int o = 0; o < 10; ++o) sacc[o] = fmaf(bb[o]*inv, u[o], sacc[o]);
    }
  }
  #pragma unroll
  for (int o = 0; o < 10; ++o) {
    sacc[o] += __shfl_xor(sacc[o], 16, 64);
    sacc[o] += __shfl_xor(sacc[o], 32, 64);
  }
  __shared__ float red[4][160];
  if (lane < 16) {
    #pragma unroll
    for (int o = 0; o < 10; ++o) red[wv][o*16 + d] = sacc[o];
  }
  __syncthreads();
  if (tid < 160) {
    float s = red[0][tid] + red[1][tid] + red[2][tid] + red[3][tid];
    cpart[((size_t)b*7 + sl)*160 + tid] = s;
  }
}

__global__ __launch_bounds__(160) void cls_finish(const float* __restrict__ cpart,
                                                  float* __restrict__ vout, float fac) {
  int b = blockIdx.x, od = threadIdx.x;
  float s = 0.f;
  #pragma unroll
  for (int sl = 0; sl < 7; ++sl) s += cpart[((size_t)b*7 + sl)*160 + od];
  s *= fac;
  float nrm = s*s;
  #pragma unroll
  for (int off = 8; off; off >>= 1) nrm += __shfl_xor(nrm, off, 16);
  float sc = nrm / ((1.f + nrm)*sqrtf(nrm + 1e-6f));
  vout[(size_t)b*160 + od] = s*sc;
}

// ---------------- host launch ----------------
extern "C" void kernel_launch(void* const* d_in, const int* in_sizes, int n_in,
                              void* d_out, int out_size, void* d_ws, size_t ws_size,
                              hipStream_t stream) {
  const float* images = (const float*)d_in[0];
  const float* w1  = (const float*)d_in[1];
  const float* g1  = (const float*)d_in[2];
  const float* b1  = (const float*)d_in[3];
  const float* w2  = (const float*)d_in[4];
  const float* g2  = (const float*)d_in[5];
  const float* b2  = (const float*)d_in[6];
  const float* w3  = (const float*)d_in[7];
  const float* g3  = (const float*)d_in[8];
  const float* b3  = (const float*)d_in[9];
  const float* wp  = (const float*)d_in[10];
  const float* bp  = (const float*)d_in[11];
  const float* wcc = (const float*)d_in[12];
  const float* wcl = (const float*)d_in[13];
  float* out = (float*)d_out;
  float* ws  = (float*)d_ws;

  // persistent regions (float offsets)
  float* t1    = ws + 0;            // 3,145,728
  float* t2    = ws + 3145728;      // 1,572,864
  float* t3    = ws + 4718592;      // 3,145,728
  float* pc    = ws + 7864320;      //   602,112
  float* uu    = ws + 8466432;      // 5,419,008
  float* u2b   = ws + 13885440;     //   602,112
  unsigned short* uh2b = (unsigned short*)(ws + 14487552);  // 8,028,160 ushorts
  float* b2l   = ws + 22515712;     //   501,760
  float* scrC  = ws + 23017472;     //   501,760 (BN stats during convs, cpart during class)
  float* v2    = ws + 23519232;     //    10,240
  float* spart = ws + 23529472;     //     3,072
  float* ssc1  = ws + 23532544;     //        96
  float* ssc2  = ws + 23532640;     //       192
  float* ssc3  = ws + 23532832;     //       384
  float* U     = ws + 23533312;     // arena, 10,838,016 f32 (conv transients)
  __hip_bfloat16* uhc = (__hip_bfloat16*)(ws + 34371328);   // 43,352,064 bf16 (one 32-img chunk)

  // split/reordered weights live in dead `uu` region (dead until uu_gather)
  unsigned short* wh2 = (unsigned short*)(uu + 0);
  unsigned short* wl2 = (unsigned short*)(uu + 20736);
  unsigned short* wh3 = (unsigned short*)(uu + 41472);
  unsigned short* wl3 = (unsigned short*)(uu + 124416);
  unsigned short* whp = (unsigned short*)(uu + 207360);
  unsigned short* wlp = (unsigned short*)(uu + 373248);

  // phase transients in the U arena
  unsigned short* x2h = (unsigned short*)(U + 0);
  unsigned short* x2l = (unsigned short*)(U + 1775616);
  float*          part2 = U + 3551232;                    // 3x96x16384
  unsigned short* x3h = (unsigned short*)(U + 0);
  unsigned short* x3l = (unsigned short*)(U + 995328);
  unsigned short* xph = (unsigned short*)(U + 0);
  unsigned short* xpl = (unsigned short*)(U + 1572864);
  float*          partp = U + 3145728;                    // 8x192x3136

  const int B = 64;

  // merged weight splits
  split_w_all<<<2106,256,0,stream>>>(w2, w3, wp, wh2, wl2, wh3, wl3, whp, wlp);

  // conv1 + BN1 stats
  conv1_fused<<<2048,192,0,stream>>>(images, w1, t1);
  bn_partial<48,1024,8><<<48*8,256,0,stream>>>(t1, spart, B);
  bn_final<48,8><<<1,64,0,stream>>>(spart, g1, b1, ssc1, 65536);

  // conv2: BN1+ReLU+split (with halos), MFMA split-K=3, reduce+stats
  bn_split_nhwc<48,32,32,1><<<64*34,256,0,stream>>>(t1, ssc1, x2h, x2l);
  conv_mfma<48,34,34,16,16,2,3><<<dim3(2,128,3),256,0,stream>>>(x2h, x2l, wh2, wl2, part2, 96, B);
  splitk_reduce<96,256,3,false,true><<<6144,256,0,stream>>>(part2, nullptr, t2, scrC, B);
  bn_final<96,64><<<1,128,0,stream>>>(scrC, g2, b2, ssc2, 16384);

  // conv3: direct NCHW write (split-K=1), stats via bn_partial
  bn_split_nhwc<96,16,16,1><<<64*18,256,0,stream>>>(t2, ssc2, x3h, x3l);
  conv_mfma<96,18,18,16,16,1,1><<<dim3(3,128,1),256,0,stream>>>(x3h, x3l, wh3, wl3, t3, 192, B);
  bn_partial<192,256,8><<<192*8,256,0,stream>>>(t3, spart, B);
  bn_final<192,8><<<1,192,0,stream>>>(spart, g3, b3, ssc3, 16384);

  // primary caps conv + bias, then squash
  bn_split_nhwc<192,16,16,0><<<64*16,256,0,stream>>>(t3, ssc3, xph, xpl);
  conv_mfma<192,16,16,7,7,2,8><<<dim3(3,25,8),256,0,stream>>>(xph, xpl, whp, wlp, partp, 192, B);
  splitk_reduce<192,49,8,true,false><<<2352,256,0,stream>>>(partp, bp, pc, nullptr, B);
  squash_pc<<<196,256,0,stream>>>(pc, 50176);

  // uu gather
  uu_gather<<<21168,256,0,stream>>>(pc, uu, B);
  // ConvCaps einsum (wide stores) + register-stash fused routing, 2 chunks of 32 images
  for (int cb = 0; cb < 2; ++cb) {
    cc_einsum3<<<dim3(144,25),192,0,stream>>>(uu, wcc, uhc, cb*1568, 1568);
    cc_route<<<1568,384,0,stream>>>(uhc, u2b, cb*1568);
  }
  // Class caps einsum (bf16) + wave-local routing
  class_einsum<<<784,320,0,stream>>>(u2b, wcl, uh2b, B);
  cls_pass<0><<<dim3(64,7),256,0,stream>>>(uh2b, v2, b2l, scrC);
  cls_finish<<<64,160,0,stream>>>(scrC, v2, 0.1f);
  cls_pass<1><<<dim3(64,7),256,0,stream>>>(uh2b, v2, b2l, scrC);
  cls_finish<<<64,160,0,stream>>>(scrC, v2, 1.0f);
  cls_pass<2><<<dim3(64,7),256,0,stream>>>(uh2b, v2, b2l, scrC);
  cls_finish<<<64,160,0,stream>>>(scrC, out, 1.0f);
  (void)in_sizes; (void)n_in; (void)out_size; (void)ws_size;
}

// Round 15
// 372.719 us; speedup vs baseline: 1.6820x; 1.0215x over previous
//
#include <hip/hip_runtime.h>
#include <hip/hip_bf16.h>

typedef __attribute__((ext_vector_type(4))) short short4v;
typedef __attribute__((ext_vector_type(8))) short short8v;
typedef __attribute__((ext_vector_type(16))) float f32x16;

union frag8 { short8v v8; struct { short4v lo, hi; } p; };

__device__ __forceinline__ unsigned short f2bf(float v) {
  unsigned u = __float_as_uint(v);
  unsigned r = u + 0x7fffu + ((u >> 16) & 1u);
  return (unsigned short)(r >> 16);
}
__device__ __forceinline__ float bf2f(unsigned short h) {
  return __uint_as_float(((unsigned)h) << 16);
}

// ---------------- conv1: one block per (b,h), LDS input slab, weights in regs ----------------
__global__ __launch_bounds__(192) void conv1_fused(const float* __restrict__ images,
                                                   const float* __restrict__ w1,
                                                   float* __restrict__ out) {
  int b = blockIdx.x >> 5, h = blockIdx.x & 31;
  __shared__ __align__(16) float lin[3][3][36];
  int tid = threadIdx.x;
  for (int e = tid; e < 324; e += 192) {
    int ci = e / 108, rem = e % 108, ki = rem / 36, wi = rem % 36;
    int row = h + ki - 1, col = wi - 1;
    float v = 0.f;
    if (row >= 0 && row < 32 && col >= 0 && col < 32)
      v = images[((size_t)(b*3 + ci)*32 + row)*32 + col];
    lin[ci][ki][wi] = v;
  }
  int co = tid >> 2, ws = tid & 3;
  float wr[27];
  #pragma unroll
  for (int j = 0; j < 27; ++j) wr[j] = w1[co*27 + j];
  __syncthreads();
  float o[8];
  #pragma unroll
  for (int j = 0; j < 8; ++j) o[j] = 0.f;
  #pragma unroll
  for (int ci = 0; ci < 3; ++ci)
    #pragma unroll
    for (int ki = 0; ki < 3; ++ki) {
      float4 q0 = *(const float4*)&lin[ci][ki][ws*8];
      float4 q1 = *(const float4*)&lin[ci][ki][ws*8+4];
      float4 q2 = *(const float4*)&lin[ci][ki][ws*8+8];
      float r[12] = {q0.x,q0.y,q0.z,q0.w,q1.x,q1.y,q1.z,q1.w,q2.x,q2.y,q2.z,q2.w};
      #pragma unroll
      for (int kj = 0; kj < 3; ++kj) {
        float wv = wr[(ci*3+ki)*3+kj];
        #pragma unroll
        for (int j = 0; j < 8; ++j) o[j] = fmaf(r[j+kj], wv, o[j]);
      }
    }
  float* dst = out + (((size_t)(b*48+co)*32 + h)*32 + ws*8);
  *(float4*)dst       = make_float4(o[0],o[1],o[2],o[3]);
  *(float4*)(dst + 4) = make_float4(o[4],o[5],o[6],o[7]);
}

// ---------------- merged weight split+reorder for conv2/conv3/primary ----------------
__device__ __forceinline__ void split_one(const float* w, unsigned short* wh,
                                          unsigned short* wl, int CI, int i) {
  int K = CI*9;
  int co = i / K, rem = i % K, tap = rem / CI, ci = rem % CI;
  float v = w[(co*CI + ci)*9 + tap];
  unsigned short h = f2bf(v);
  wh[i] = h;
  wl[i] = f2bf(v - bf2f(h));
}
__global__ void split_w_all(const float* __restrict__ w2, const float* __restrict__ w3,
                            const float* __restrict__ wp,
                            unsigned short* wh2, unsigned short* wl2,
                            unsigned short* wh3, unsigned short* wl3,
                            unsigned short* whp, unsigned short* wlp) {
  int i = blockIdx.x*256 + threadIdx.x;
  if (i < 41472) split_one(w2, wh2, wl2, 48, i);
  else if (i < 207360) split_one(w3, wh3, wl3, 96, i - 41472);
  else if (i < 539136) split_one(wp, whp, wlp, 192, i - 207360);
}

// ---------------- BN affine + ReLU + split to padded NHWC bf16 hi/lo (writes halos) ----------------
template<int C,int H,int W,int P>
__global__ void bn_split_nhwc(const float* __restrict__ in, const float* __restrict__ sc,
                              unsigned short* __restrict__ xh, unsigned short* __restrict__ xl) {
  constexpr int HP = H + 2*P, WP = W + 2*P;
  int b = blockIdx.x / HP, hp = blockIdx.x % HP;
  int h = hp - P;
  for (int e = threadIdx.x; e < WP*C; e += 256) {
    int wp = e / C, c = e % C;
    int w = wp - P;
    float v = 0.f;
    if (h >= 0 && h < H && w >= 0 && w < W) {
      v = in[((size_t)(b*C + c)*H + h)*W + w];
      v = fmaf(v, sc[c*2], sc[c*2+1]);
      v = v > 0.f ? v : 0.f;
    }
    unsigned short hh = f2bf(v);
    size_t o = ((size_t)(b*HP + hp)*WP + wp)*C + c;
    xh[o] = hh;
    xl[o] = f2bf(v - bf2f(hh));
  }
}

// ---------------- MFMA implicit-GEMM conv; SPLITK==1 writes NCHW directly ----------------
template<int CI,int HIP,int WIP,int HO,int WO,int STR,int SPLITK>
__global__ __launch_bounds__(256,4) void conv_mfma(
    const unsigned short* __restrict__ xh, const unsigned short* __restrict__ xl,
    const unsigned short* __restrict__ wh, const unsigned short* __restrict__ wl,
    float* __restrict__ part, int CO, int B) {
  constexpr int K = CI*9, NSP = HO*WO, KCH = K/SPLITK, LDA = 36;
  const int NTOT = B*NSP;
  const int m0 = blockIdx.x*64, n0 = blockIdx.y*128, ks = blockIdx.z;
  __shared__ unsigned short Ah[64*LDA], Al[64*LDA], Bh[128*LDA], Bl[128*LDA];
  const int tid = threadIdx.x, lane = tid & 63, wid = tid >> 6;
  const int wm = wid >> 1, wn = wid & 1;
  const int arow = tid >> 2, ak0 = (tid & 3)*8;
  const bool aok = (m0 + arow) < CO;
  const size_t abase = (size_t)(m0 + arow)*K;
  int brow[2], bk0[2];
  size_t bbase[2];
  #pragma unroll
  for (int i = 0; i < 2; ++i) {
    int e = tid + i*256;
    brow[i] = e >> 2; bk0[i] = (e & 3)*8;
    int nn = n0 + brow[i]; if (nn > NTOT-1) nn = NTOT-1;
    int bb = nn / NSP, sp = nn % NSP;
    int ho = sp / WO, wo = sp % WO;
    bbase[i] = ((size_t)bb*HIP + ho*STR)*WIP + wo*STR;
  }
  f32x16 acc0 = (f32x16)0.f, acc1 = (f32x16)0.f;
  const int kBeg = ks*KCH, kEnd = kBeg + KCH;
  for (int kc = kBeg; kc < kEnd; kc += 32) {
    const int kLim = (kEnd - kc) < 32 ? (kEnd - kc) : 32;
    {
      frag8 vh, vl;
      vh.v8 = (short8v)(short)0; vl.v8 = (short8v)(short)0;
      if (aok && ak0 < kLim) {
        size_t off = abase + kc + ak0;
        vh.v8 = *(const short8v*)(wh + off);
        vl.v8 = *(const short8v*)(wl + off);
      }
      int lo_ = arow*LDA + ak0;
      *(short4v*)(Ah + lo_) = vh.p.lo; *(short4v*)(Ah + lo_ + 4) = vh.p.hi;
      *(short4v*)(Al + lo_) = vl.p.lo; *(short4v*)(Al + lo_ + 4) = vl.p.hi;
    }
    #pragma unroll
    for (int i = 0; i < 2; ++i) {
      frag8 vh, vl;
      vh.v8 = (short8v)(short)0; vl.v8 = (short8v)(short)0;
      if (bk0[i] < kLim) {
        int kg = kc + bk0[i];
        int tap = kg / CI, ci0 = kg - tap*CI;
        int dh = tap / 3, dw = tap - dh*3;
        size_t off = (bbase[i] + (size_t)dh*WIP + dw)*CI + ci0;
        vh.v8 = *(const short8v*)(xh + off);
        vl.v8 = *(const short8v*)(xl + off);
      }
      int lo_ = brow[i]*LDA + bk0[i];
      *(short4v*)(Bh + lo_) = vh.p.lo; *(short4v*)(Bh + lo_ + 4) = vh.p.hi;
      *(short4v*)(Bl + lo_) = vl.p.lo; *(short4v*)(Bl + lo_ + 4) = vl.p.hi;
    }
    __syncthreads();
    #pragma unroll
    for (int kst = 0; kst < 2; ++kst) {
      const int kb = kst*16 + 8*(lane >> 5);
      const int ar = wm*32 + (lane & 31);
      frag8 ah, al;
      { int o = ar*LDA + kb;
        ah.p.lo = *(const short4v*)(Ah + o); ah.p.hi = *(const short4v*)(Ah + o + 4);
        al.p.lo = *(const short4v*)(Al + o); al.p.hi = *(const short4v*)(Al + o + 4); }
      const int br = wn*64 + (lane & 31);
      frag8 bh0, bl0, bh1, bl1;
      { int o = br*LDA + kb;
        bh0.p.lo = *(const short4v*)(Bh + o); bh0.p.hi = *(const short4v*)(Bh + o + 4);
        bl0.p.lo = *(const short4v*)(Bl + o); bl0.p.hi = *(const short4v*)(Bl + o + 4); }
      { int o = (br+32)*LDA + kb;
        bh1.p.lo = *(const short4v*)(Bh + o); bh1.p.hi = *(const short4v*)(Bh + o + 4);
        bl1.p.lo = *(const short4v*)(Bl + o); bl1.p.hi = *(const short4v*)(Bl + o + 4); }
      acc0 = __builtin_amdgcn_mfma_f32_32x32x16_bf16(ah.v8, bh0.v8, acc0, 0, 0, 0);
      acc0 = __builtin_amdgcn_mfma_f32_32x32x16_bf16(ah.v8, bl0.v8, acc0, 0, 0, 0);
      acc0 = __builtin_amdgcn_mfma_f32_32x32x16_bf16(al.v8, bh0.v8, acc0, 0, 0, 0);
      acc1 = __builtin_amdgcn_mfma_f32_32x32x16_bf16(ah.v8, bh1.v8, acc1, 0, 0, 0);
      acc1 = __builtin_amdgcn_mfma_f32_32x32x16_bf16(ah.v8, bl1.v8, acc1, 0, 0, 0);
      acc1 = __builtin_amdgcn_mfma_f32_32x32x16_bf16(al.v8, bh1.v8, acc1, 0, 0, 0);
    }
    __syncthreads();
  }
  #pragma unroll
  for (int ns = 0; ns < 2; ++ns) {
    f32x16 a = ns ? acc1 : acc0;
    #pragma unroll
    for (int r = 0; r < 16; ++r) {
      int row = (r & 3) + 8*(r >> 2) + 4*(lane >> 5);
      int m = m0 + wm*32 + row;
      int n = n0 + wn*64 + ns*32 + (lane & 31);
      if (m < CO && n < NTOT) {
        if (SPLITK == 1) {
          int b = n / NSP, sp = n % NSP;
          part[((size_t)b*CO + m)*NSP + sp] = a[r];
        } else {
          part[((size_t)ks*CO + m)*NTOT + n] = a[r];
        }
      }
    }
  }
}

// ---------------- split-K reduce (+bias, + optional fused BN partial stats) ----------------
template<int CO,int NSP,int SPLITK,bool BIAS,bool STATS>
__global__ void splitk_reduce(const float* __restrict__ part, const float* __restrict__ bias,
                              float* __restrict__ out, float* __restrict__ stats, int B) {
  const int NTOT = B*NSP;
  int i = blockIdx.x*256 + threadIdx.x;
  bool valid = i < CO*NTOT;
  float s = 0.f;
  if (valid) {
    int co = i / NTOT, n = i % NTOT;
    #pragma unroll
    for (int ks = 0; ks < SPLITK; ++ks) s += part[(size_t)(ks*CO + co)*NTOT + n];
    if (BIAS) s += bias[co];
    int b = n / NSP, sp = n % NSP;
    out[((size_t)b*CO + co)*NSP + sp] = s;
  }
  if (STATS) {
    float sum = valid ? s : 0.f, sq = valid ? s*s : 0.f;
    #pragma unroll
    for (int off = 32; off; off >>= 1) {
      sum += __shfl_down(sum, off, 64);
      sq  += __shfl_down(sq,  off, 64);
    }
    __shared__ float ls[2][4];
    int lane = threadIdx.x & 63, wv = threadIdx.x >> 6;
    if (lane == 0) { ls[0][wv] = sum; ls[1][wv] = sq; }
    __syncthreads();
    if (threadIdx.x == 0) {
      float S = 0.f, Q = 0.f;
      #pragma unroll
      for (int j = 0; j < 4; ++j) { S += ls[0][j]; Q += ls[1][j]; }
      int bpc = NTOT/256;
      int co = blockIdx.x / bpc, slice = blockIdx.x % bpc;
      stats[(co*bpc + slice)*2 + 0] = S;
      stats[(co*bpc + slice)*2 + 1] = Q;
    }
  }
}

// ---------------- BN stats ----------------
template<int C,int HW,int SLICES>
__global__ void bn_partial(const float* __restrict__ x, float* __restrict__ part, int B) {
  int c = blockIdx.x / SLICES, s = blockIdx.x % SLICES;
  int bpp = B / SLICES;
  float sum = 0.f, sq = 0.f;
  for (int b = s*bpp; b < (s+1)*bpp; ++b) {
    const float* p = x + ((size_t)b*C + c)*HW;
    for (int i = threadIdx.x; i < HW; i += blockDim.x) {
      float v = p[i]; sum += v; sq += v*v;
    }
  }
  #pragma unroll
  for (int off = 32; off; off >>= 1) {
    sum += __shfl_down(sum, off, 64);
    sq  += __shfl_down(sq,  off, 64);
  }
  __shared__ float ls[2][4];
  int lane = threadIdx.x & 63, wv = threadIdx.x >> 6;
  if (lane == 0) { ls[0][wv] = sum; ls[1][wv] = sq; }
  __syncthreads();
  if (threadIdx.x == 0) {
    float S = 0.f, Q = 0.f;
    #pragma unroll
    for (int i = 0; i < 4; ++i) { S += ls[0][i]; Q += ls[1][i]; }
    part[(c*SLICES+s)*2+0] = S; part[(c*SLICES+s)*2+1] = Q;
  }
}

template<int C,int SLICES>
__global__ void bn_final(const float* __restrict__ part, const float* __restrict__ g,
                         const float* __restrict__ bta, float* __restrict__ sc, int NHW) {
  int c = blockIdx.x*blockDim.x + threadIdx.x;
  if (c >= C) return;
  float S = 0.f, Q = 0.f;
  for (int s = 0; s < SLICES; ++s) { S += part[(c*SLICES+s)*2]; Q += part[(c*SLICES+s)*2+1]; }
  float m = S / NHW, v = Q / NHW - m*m;
  float inv = rsqrtf(v + 1e-5f);
  float a = g[c] * inv;
  sc[c*2] = a; sc[c*2+1] = bta[c] - m*a;
}

// ---------------- squash primary caps in place ----------------
__global__ void squash_pc(float* __restrict__ pc, int ncaps) {
  int i = blockIdx.x*blockDim.x + threadIdx.x;
  if (i >= ncaps) return;
  float* p = pc + (size_t)i*12;
  float v[12]; float s = 0.f;
  #pragma unroll
  for (int d = 0; d < 12; ++d) { v[d] = p[d]; s += v[d]*v[d]; }
  float sc = s / ((1.f + s)*sqrtf(s + 1e-6f));
  #pragma unroll
  for (int d = 0; d < 12; ++d) p[d] = v[d]*sc;
}

// ---------------- uu gather ----------------
__global__ void uu_gather(const float* __restrict__ sq, float* __restrict__ uu, int B) {
  int idx = blockIdx.x*blockDim.x + threadIdx.x;
  int total = B*49*144*12;
  if (idx >= total) return;
  int ii = idx % 12; int t0 = idx / 12;
  int kk = t0 % 144; t0 /= 144;
  int tt = t0 % 49;  int b = t0 / 49;
  int f = tt*1728 + kk*12 + ii;
  int c = f / 441; int r = f - c*441;
  int k = r / 49;  int sp = r - k*49;
  int y = sp / 7, x = sp - y*7;
  int iy = y + k/3 - 1, ix = x + (k%3) - 1;
  float val = 0.f;
  if (iy >= 0 && iy < 7 && ix >= 0 && ix < 7)
    val = sq[((size_t)(b*192 + c)*7 + iy)*7 + ix];
  uu[idx] = val;
}

// ---------------- ConvCaps einsum: 4 o's + 16 m's per thread, ushort4 stores ----------------
__global__ __launch_bounds__(192) void cc_einsum3(const float* __restrict__ uu,
                                                  const float* __restrict__ wcc,
                                                  __hip_bfloat16* __restrict__ uhat,
                                                  int row0, int nrows) {
  const int k  = blockIdx.x;
  const int m0 = blockIdx.y * 64;
  const int tid = threadIdx.x;
  const int m4 = tid / 48, oq = tid % 48;
  float wr[4][12];
  #pragma unroll
  for (int c = 0; c < 4; ++c) {
    const float4* wp4 = (const float4*)(wcc + ((size_t)k*192 + oq*4 + c)*12);
    float4 a = wp4[0], b = wp4[1], d = wp4[2];
    wr[c][0]=a.x; wr[c][1]=a.y; wr[c][2]=a.z; wr[c][3]=a.w;
    wr[c][4]=b.x; wr[c][5]=b.y; wr[c][6]=b.z; wr[c][7]=b.w;
    wr[c][8]=d.x; wr[c][9]=d.y; wr[c][10]=d.z; wr[c][11]=d.w;
  }
  int mmax = nrows - m0; if (mmax > 64) mmax = 64;
  #pragma unroll 4
  for (int mi = 0; mi < 16; ++mi) {
    int m = m4*16 + mi;
    if (m >= mmax) break;
    const float4* ar = (const float4*)(uu + ((size_t)(row0+m0+m)*144 + k)*12);
    float4 a0 = ar[0], a1 = ar[1], a2 = ar[2];
    float af[12] = {a0.x,a0.y,a0.z,a0.w,a1.x,a1.y,a1.z,a1.w,a2.x,a2.y,a2.z,a2.w};
    ushort4 pkt;
    unsigned short* pp = (unsigned short*)&pkt;
    #pragma unroll
    for (int c = 0; c < 4; ++c) {
      float acc = 0.f;
      #pragma unroll
      for (int i = 0; i < 12; ++i) acc = fmaf(wr[c][i], af[i], acc);
      pp[c] = f2bf(acc);
    }
    unsigned short* up = (unsigned short*)uhat + ((size_t)(m0+m)*144 + k)*192 + oq*4;
    *(ushort4*)up = pkt;
  }
}

// ---------------- ConvCaps routing: register stash, fused 3-pass, no-max softmax ------------
// 384 threads = 24 groups x 16 lanes. lane=(g,oc); group g owns k = g+24j, j=0..5.
// launch_bounds(384,4): proven no-spill config. Softmax without max-subtraction
// (logits bounded |b|<~8 -> exp safe in fp32; ratio mathematically identical).
__global__ __launch_bounds__(384,4) void cc_route(const __hip_bfloat16* __restrict__ uhat,
                                                  float* __restrict__ u2, int rowOff) {
  const int row = blockIdx.x;
  const unsigned short* __restrict__ uh = (const unsigned short*)uhat + (size_t)row*27648;
  __shared__ float red[6][192];
  __shared__ float sraw[192];
  __shared__ float vsh[192];
  const int tid = threadIdx.x, lane = tid & 63, wv = tid >> 6;
  const int g = tid >> 4, oc = tid & 15;
  uint2 st[6][3];
  float blog[6];
  #pragma unroll
  for (int j = 0; j < 6; ++j) blog[j] = 0.f;
  float sacc[12];

  // ---- pass 0: load + stash + uniform-c sum
  #pragma unroll
  for (int d = 0; d < 12; ++d) sacc[d] = 0.f;
  #pragma unroll
  for (int j = 0; j < 6; ++j) {
    const unsigned short* up = uh + (g + 24*j)*192 + oc*12;
    uint2 q0 = *(const uint2*)up;
    uint2 q1 = *(const uint2*)(up + 4);
    uint2 q2 = *(const uint2*)(up + 8);
    st[j][0] = q0; st[j][1] = q1; st[j][2] = q2;
    sacc[0] += bf2f((unsigned short)(q0.x & 0xffff)); sacc[1] += bf2f((unsigned short)(q0.x >> 16));
    sacc[2] += bf2f((unsigned short)(q0.y & 0xffff)); sacc[3] += bf2f((unsigned short)(q0.y >> 16));
    sacc[4] += bf2f((unsigned short)(q1.x & 0xffff)); sacc[5] += bf2f((unsigned short)(q1.x >> 16));
    sacc[6] += bf2f((unsigned short)(q1.y & 0xffff)); sacc[7] += bf2f((unsigned short)(q1.y >> 16));
    sacc[8] += bf2f((unsigned short)(q2.x & 0xffff)); sacc[9] += bf2f((unsigned short)(q2.x >> 16));
    sacc[10] += bf2f((unsigned short)(q2.y & 0xffff)); sacc[11] += bf2f((unsigned short)(q2.y >> 16));
  }
  #pragma unroll
  for (int d = 0; d < 12; ++d) {
    sacc[d] += __shfl_xor(sacc[d], 16, 64);
    sacc[d] += __shfl_xor(sacc[d], 32, 64);
  }
  if (lane < 16) {
    #pragma unroll
    for (int d = 0; d < 12; ++d) red[wv][oc*12 + d] = sacc[d];
  }
  __syncthreads();
  if (tid < 192) {
    float s = (red[0][tid] + red[1][tid] + red[2][tid]
             + red[3][tid] + red[4][tid] + red[5][tid]) * 0.0625f;
    sraw[tid] = s;
  }
  __syncthreads();
  if (tid < 192) {
    int qc = tid / 12;
    float nrm = 0.f;
    #pragma unroll
    for (int d = 0; d < 12; ++d) { float v = sraw[qc*12 + d]; nrm += v*v; }
    float sc = nrm / ((1.f + nrm)*sqrtf(nrm + 1e-6f));
    vsh[tid] = sraw[tid]*sc;
  }
  __syncthreads();

  // ---- passes 1,2: all-register data, no-max softmax
  #pragma unroll
  for (int r = 1; r < 3; ++r) {
    float vq[12];
    #pragma unroll
    for (int d = 0; d < 12; ++d) vq[d] = vsh[oc*12 + d];
    #pragma unroll
    for (int d = 0; d < 12; ++d) sacc[d] = 0.f;
    #pragma unroll
    for (int j = 0; j < 6; ++j) {
      uint2 q0 = st[j][0], q1 = st[j][1], q2 = st[j][2];
      float uf[12];
      uf[0] = bf2f((unsigned short)(q0.x & 0xffff)); uf[1] = bf2f((unsigned short)(q0.x >> 16));
      uf[2] = bf2f((unsigned short)(q0.y & 0xffff)); uf[3] = bf2f((unsigned short)(q0.y >> 16));
      uf[4] = bf2f((unsigned short)(q1.x & 0xffff)); uf[5] = bf2f((unsigned short)(q1.x >> 16));
      uf[6] = bf2f((unsigned short)(q1.y & 0xffff)); uf[7] = bf2f((unsigned short)(q1.y >> 16));
      uf[8] = bf2f((unsigned short)(q2.x & 0xffff)); uf[9] = bf2f((unsigned short)(q2.x >> 16));
      uf[10] = bf2f((unsigned short)(q2.y & 0xffff)); uf[11] = bf2f((unsigned short)(q2.y >> 16));
      float dot = 0.f;
      #pragma unroll
      for (int d = 0; d < 12; ++d) dot = fmaf(vq[d], uf[d], dot);
      blog[j] += dot;
      float e = __expf(blog[j]);
      float es = e;
      #pragma unroll
      for (int off = 1; off < 16; off <<= 1) es += __shfl_xor(es, off, 16);
      float c = e / es;
      #pragma unroll
      for (int d = 0; d < 12; ++d) sacc[d] = fmaf(c, uf[d], sacc[d]);
    }
    #pragma unroll
    for (int d = 0; d < 12; ++d) {
      sacc[d] += __shfl_xor(sacc[d], 16, 64);
      sacc[d] += __shfl_xor(sacc[d], 32, 64);
    }
    if (lane < 16) {
      #pragma unroll
      for (int d = 0; d < 12; ++d) red[wv][oc*12 + d] = sacc[d];
    }
    __syncthreads();
    if (tid < 192) {
      sraw[tid] = red[0][tid] + red[1][tid] + red[2][tid]
                + red[3][tid] + red[4][tid] + red[5][tid];
    }
    __syncthreads();
    if (tid < 192) {
      int qc = tid / 12;
      float nrm = 0.f;
      #pragma unroll
      for (int d = 0; d < 12; ++d) { float v = sraw[qc*12 + d]; nrm += v*v; }
      float sc = nrm / ((1.f + nrm)*sqrtf(nrm + 1e-6f));
      vsh[tid] = sraw[tid]*sc;
    }
    __syncthreads();
  }
  if (tid < 192) u2[((size_t)(rowOff + row))*192 + tid] = vsh[tid];
}

// ---------------- Class caps einsum (bf16 output) ----------------
__global__ void class_einsum(const float* __restrict__ u2, const float* __restrict__ wcl,
                             unsigned short* __restrict__ uhat2, int B) {
  int n = blockIdx.x;
  __shared__ float u2l[64][12];
  int tid = threadIdx.x;
  for (int e = tid; e < 64*12; e += 320) {
    int b = e / 12, i = e % 12;
    u2l[b][i] = u2[(size_t)b*9408 + n*12 + i];
  }
  __syncthreads();
  int od = tid % 160, bh = tid / 160;
  int o = od >> 4, d = od & 15;
  float w[12];
  #pragma unroll
  for (int i = 0; i < 12; ++i) w[i] = wcl[(size_t)n*1920 + o*192 + d*12 + i];
  for (int b = bh*32; b < bh*32+32; ++b) {
    float acc = 0.f;
    #pragma unroll
    for (int i = 0; i < 12; ++i) acc = fmaf(w[i], u2l[b][i], acc);
    uhat2[((size_t)b*784 + n)*160 + od] = f2bf(acc);
  }
}

// ---------------- class routing: wave-local pass, no-max softmax ----------------
template<int MODE>
__global__ __launch_bounds__(256) void cls_pass(const unsigned short* __restrict__ uh2b,
                                                const float* __restrict__ vprev,
                                                float* __restrict__ b2l,
                                                float* __restrict__ cpart) {
  const int b = blockIdx.x, sl = blockIdx.y;   // sl 0..6
  const int tid = threadIdx.x, lane = tid & 63, wv = tid >> 6;
  const int nl = lane >> 4, d = lane & 15;
  float v[10];
  if (MODE != 0) {
    #pragma unroll
    for (int o = 0; o < 10; ++o) v[o] = vprev[b*160 + o*16 + d];
  }
  float sacc[10];
  #pragma unroll
  for (int o = 0; o < 10; ++o) sacc[o] = 0.f;
  for (int step = 0; step < 7; ++step) {
    const int n = sl*112 + step*16 + wv*4 + nl;
    const unsigned short* up = uh2b + ((size_t)b*784 + n)*160 + d;
    float u[10];
    #pragma unroll
    for (int o = 0; o < 10; ++o) u[o] = bf2f(up[o*16]);
    if (MODE == 0) {
      #pragma unroll
      for (int o = 0; o < 10; ++o) sacc[o] += u[o];
    } else {
      float bb[10];
      #pragma unroll
      for (int o = 0; o < 10; ++o) {
        float t = v[o]*u[o];
        #pragma unroll
        for (int off = 8; off; off >>= 1) t += __shfl_xor(t, off, 16);
        bb[o] = t;
      }
      if (MODE == 2) {
        #pragma unroll
        for (int o = 0; o < 10; ++o) bb[o] += b2l[((size_t)b*784 + n)*10 + o];
      }
      if (MODE == 1 && d < 10) b2l[((size_t)b*784 + n)*10 + d] = bb[d];
      float es = 0.f;
      #pragma unroll
      for (int o = 0; o < 10; ++o) { bb[o] = __expf(bb[o]); es += bb[o]; }
      float inv = 1.f/es;
      #pragma unroll
      for (int o = 0; o < 10; ++o) sacc[o] = fmaf(bb[o]*inv, u[o], sacc[o]);
    }
  }
  #pragma unroll
  for (int o = 0; o < 10; ++o) {
    sacc[o] += __shfl_xor(sacc[o], 16, 64);
    sacc[o] += __shfl_xor(sacc[o], 32, 64);
  }
  __shared__ float red[4][160];
  if (lane < 16) {
    #pragma unroll
    for (int o = 0; o < 10; ++o) red[wv][o*16 + d] = sacc[o];
  }
  __syncthreads();
  if (tid < 160) {
    float s = red[0][tid] + red[1][tid] + red[2][tid] + red[3][tid];
    cpart[((size_t)b*7 + sl)*160 + tid] = s;
  }
}

__global__ __launch_bounds__(160) void cls_finish(const float* __restrict__ cpart,
                                                  float* __restrict__ vout, float fac) {
  int b = blockIdx.x, od = threadIdx.x;
  float s = 0.f;
  #pragma unroll
  for (int sl = 0; sl < 7; ++sl) s += cpart[((size_t)b*7 + sl)*160 + od];
  s *= fac;
  float nrm = s*s;
  #pragma unroll
  for (int off = 8; off; off >>= 1) nrm += __shfl_xor(nrm, off, 16);
  float sc = nrm / ((1.f + nrm)*sqrtf(nrm + 1e-6f));
  vout[(size_t)b*160 + od] = s*sc;
}

// ---------------- host launch ----------------
extern "C" void kernel_launch(void* const* d_in, const int* in_sizes, int n_in,
                              void* d_out, int out_size, void* d_ws, size_t ws_size,
                              hipStream_t stream) {
  const float* images = (const float*)d_in[0];
  const float* w1  = (const float*)d_in[1];
  const float* g1  = (const float*)d_in[2];
  const float* b1  = (const float*)d_in[3];
  const float* w2  = (const float*)d_in[4];
  const float* g2  = (const float*)d_in[5];
  const float* b2  = (const float*)d_in[6];
  const float* w3  = (const float*)d_in[7];
  const float* g3  = (const float*)d_in[8];
  const float* b3  = (const float*)d_in[9];
  const float* wp  = (const float*)d_in[10];
  const float* bp  = (const float*)d_in[11];
  const float* wcc = (const float*)d_in[12];
  const float* wcl = (const float*)d_in[13];
  float* out = (float*)d_out;
  float* ws  = (float*)d_ws;

  // persistent regions (float offsets)
  float* t1    = ws + 0;            // 3,145,728
  float* t2    = ws + 3145728;      // 1,572,864
  float* t3    = ws + 4718592;      // 3,145,728
  float* pc    = ws + 7864320;      //   602,112
  float* uu    = ws + 8466432;      // 5,419,008
  float* u2b   = ws + 13885440;     //   602,112
  unsigned short* uh2b = (unsigned short*)(ws + 14487552);  // 8,028,160 ushorts
  float* b2l   = ws + 22515712;     //   501,760
  float* scrC  = ws + 23017472;     //   501,760 (BN stats during convs, cpart during class)
  float* v2    = ws + 23519232;     //    10,240
  float* spart = ws + 23529472;     //     3,072
  float* ssc1  = ws + 23532544;     //        96
  float* ssc2  = ws + 23532640;     //       192
  float* ssc3  = ws + 23532832;     //       384
  float* U     = ws + 23533312;     // arena, 10,838,016 f32 (conv transients)
  __hip_bfloat16* uhc = (__hip_bfloat16*)(ws + 34371328);   // 43,352,064 bf16 (one 32-img chunk)

  // split/reordered weights live in dead `uu` region (dead until uu_gather)
  unsigned short* wh2 = (unsigned short*)(uu + 0);
  unsigned short* wl2 = (unsigned short*)(uu + 20736);
  unsigned short* wh3 = (unsigned short*)(uu + 41472);
  unsigned short* wl3 = (unsigned short*)(uu + 124416);
  unsigned short* whp = (unsigned short*)(uu + 207360);
  unsigned short* wlp = (unsigned short*)(uu + 373248);

  // phase transients in the U arena
  unsigned short* x2h = (unsigned short*)(U + 0);
  unsigned short* x2l = (unsigned short*)(U + 1775616);
  float*          part2 = U + 3551232;                    // 3x96x16384
  unsigned short* x3h = (unsigned short*)(U + 0);
  unsigned short* x3l = (unsigned short*)(U + 995328);
  unsigned short* xph = (unsigned short*)(U + 0);
  unsigned short* xpl = (unsigned short*)(U + 1572864);
  float*          partp = U + 3145728;                    // 8x192x3136

  const int B = 64;

  // merged weight splits
  split_w_all<<<2106,256,0,stream>>>(w2, w3, wp, wh2, wl2, wh3, wl3, whp, wlp);

  // conv1 + BN1 stats
  conv1_fused<<<2048,192,0,stream>>>(images, w1, t1);
  bn_partial<48,1024,8><<<48*8,256,0,stream>>>(t1, spart, B);
  bn_final<48,8><<<1,64,0,stream>>>(spart, g1, b1, ssc1, 65536);

  // conv2: BN1+ReLU+split (with halos), MFMA split-K=3, reduce+stats
  bn_split_nhwc<48,32,32,1><<<64*34,256,0,stream>>>(t1, ssc1, x2h, x2l);
  conv_mfma<48,34,34,16,16,2,3><<<dim3(2,128,3),256,0,stream>>>(x2h, x2l, wh2, wl2, part2, 96, B);
  splitk_reduce<96,256,3,false,true><<<6144,256,0,stream>>>(part2, nullptr, t2, scrC, B);
  bn_final<96,64><<<1,128,0,stream>>>(scrC, g2, b2, ssc2, 16384);

  // conv3: direct NCHW write (split-K=1), stats via bn_partial
  bn_split_nhwc<96,16,16,1><<<64*18,256,0,stream>>>(t2, ssc2, x3h, x3l);
  conv_mfma<96,18,18,16,16,1,1><<<dim3(3,128,1),256,0,stream>>>(x3h, x3l, wh3, wl3, t3, 192, B);
  bn_partial<192,256,8><<<192*8,256,0,stream>>>(t3, spart, B);
  bn_final<192,8><<<1,192,0,stream>>>(spart, g3, b3, ssc3, 16384);

  // primary caps conv + bias, then squash
  bn_split_nhwc<192,16,16,0><<<64*16,256,0,stream>>>(t3, ssc3, xph, xpl);
  conv_mfma<192,16,16,7,7,2,8><<<dim3(3,25,8),256,0,stream>>>(xph, xpl, whp, wlp, partp, 192, B);
  splitk_reduce<192,49,8,true,false><<<2352,256,0,stream>>>(partp, bp, pc, nullptr, B);
  squash_pc<<<196,256,0,stream>>>(pc, 50176);

  // uu gather
  uu_gather<<<21168,256,0,stream>>>(pc, uu, B);
  // ConvCaps einsum (wide stores) + register-stash fused routing, 2 chunks of 32 images
  for (int cb = 0; cb < 2; ++cb) {
    cc_einsum3<<<dim3(144,25),192,0,stream>>>(uu, wcc, uhc, cb*1568, 1568);
    cc_route<<<1568,384,0,stream>>>(uhc, u2b, cb*1568);
  }
  // Class caps einsum (bf16) + wave-local routing
  class_einsum<<<784,320,0,stream>>>(u2b, wcl, uh2b, B);
  cls_pass<0><<<dim3(64,7),256,0,stream>>>(uh2b, v2, b2l, scrC);
  cls_finish<<<64,160,0,stream>>>(scrC, v2, 0.1f);
  cls_pass<1><<<dim3(64,7),256,0,stream>>>(uh2b, v2, b2l, scrC);
  cls_finish<<<64,160,0,stream>>>(scrC, v2, 1.0f);
  cls_pass<2><<<dim3(64,7),256,0,stream>>>(uh2b, v2, b2l, scrC);
  cls_finish<<<64,160,0,stream>>>(scrC, out, 1.0f);
  (void)in_sizes; (void)n_in; (void)out_size; (void)ws_size;
}

// Round 16
// 370.856 us; speedup vs baseline: 1.6904x; 1.0050x over previous
//
#include <hip/hip_runtime.h>
#include <hip/hip_bf16.h>

typedef __attribute__((ext_vector_type(4))) short short4v;
typedef __attribute__((ext_vector_type(8))) short short8v;
typedef __attribute__((ext_vector_type(16))) float f32x16;

union frag8 { short8v v8; struct { short4v lo, hi; } p; };

__device__ __forceinline__ unsigned short f2bf(float v) {
  unsigned u = __float_as_uint(v);
  unsigned r = u + 0x7fffu + ((u >> 16) & 1u);
  return (unsigned short)(r >> 16);
}
__device__ __forceinline__ float bf2f(unsigned short h) {
  return __uint_as_float(((unsigned)h) << 16);
}

// ---------------- conv1: one block per (b,h), LDS input slab, weights in regs ----------------
__global__ __launch_bounds__(192) void conv1_fused(const float* __restrict__ images,
                                                   const float* __restrict__ w1,
                                                   float* __restrict__ out) {
  int b = blockIdx.x >> 5, h = blockIdx.x & 31;
  __shared__ __align__(16) float lin[3][3][36];
  int tid = threadIdx.x;
  for (int e = tid; e < 324; e += 192) {
    int ci = e / 108, rem = e % 108, ki = rem / 36, wi = rem % 36;
    int row = h + ki - 1, col = wi - 1;
    float v = 0.f;
    if (row >= 0 && row < 32 && col >= 0 && col < 32)
      v = images[((size_t)(b*3 + ci)*32 + row)*32 + col];
    lin[ci][ki][wi] = v;
  }
  int co = tid >> 2, ws = tid & 3;
  float wr[27];
  #pragma unroll
  for (int j = 0; j < 27; ++j) wr[j] = w1[co*27 + j];
  __syncthreads();
  float o[8];
  #pragma unroll
  for (int j = 0; j < 8; ++j) o[j] = 0.f;
  #pragma unroll
  for (int ci = 0; ci < 3; ++ci)
    #pragma unroll
    for (int ki = 0; ki < 3; ++ki) {
      float4 q0 = *(const float4*)&lin[ci][ki][ws*8];
      float4 q1 = *(const float4*)&lin[ci][ki][ws*8+4];
      float4 q2 = *(const float4*)&lin[ci][ki][ws*8+8];
      float r[12] = {q0.x,q0.y,q0.z,q0.w,q1.x,q1.y,q1.z,q1.w,q2.x,q2.y,q2.z,q2.w};
      #pragma unroll
      for (int kj = 0; kj < 3; ++kj) {
        float wv = wr[(ci*3+ki)*3+kj];
        #pragma unroll
        for (int j = 0; j < 8; ++j) o[j] = fmaf(r[j+kj], wv, o[j]);
      }
    }
  float* dst = out + (((size_t)(b*48+co)*32 + h)*32 + ws*8);
  *(float4*)dst       = make_float4(o[0],o[1],o[2],o[3]);
  *(float4*)(dst + 4) = make_float4(o[4],o[5],o[6],o[7]);
}

// ---------------- merged weight split+reorder for conv2/conv3/primary ----------------
__device__ __forceinline__ void split_one(const float* w, unsigned short* wh,
                                          unsigned short* wl, int CI, int i) {
  int K = CI*9;
  int co = i / K, rem = i % K, tap = rem / CI, ci = rem % CI;
  float v = w[(co*CI + ci)*9 + tap];
  unsigned short h = f2bf(v);
  wh[i] = h;
  wl[i] = f2bf(v - bf2f(h));
}
__global__ void split_w_all(const float* __restrict__ w2, const float* __restrict__ w3,
                            const float* __restrict__ wp,
                            unsigned short* wh2, unsigned short* wl2,
                            unsigned short* wh3, unsigned short* wl3,
                            unsigned short* whp, unsigned short* wlp) {
  int i = blockIdx.x*256 + threadIdx.x;
  if (i < 41472) split_one(w2, wh2, wl2, 48, i);
  else if (i < 207360) split_one(w3, wh3, wl3, 96, i - 41472);
  else if (i < 539136) split_one(wp, whp, wlp, 192, i - 207360);
}

// ------- BN finalize (in-block from raw stats) + affine + ReLU + split to padded NHWC -------
template<int C,int H,int W,int P,int SLICES>
__global__ void bn_split_nhwc2(const float* __restrict__ in, const float* __restrict__ stats,
                               const float* __restrict__ g, const float* __restrict__ bta,
                               unsigned short* __restrict__ xh, unsigned short* __restrict__ xl,
                               int NHW) {
  constexpr int HP = H + 2*P, WP = W + 2*P;
  __shared__ float sA[C], sB[C];
  int b = blockIdx.x / HP, hp = blockIdx.x % HP;
  int h = hp - P;
  for (int c = threadIdx.x; c < C; c += 256) {
    float S = 0.f, Q = 0.f;
    #pragma unroll 4
    for (int s = 0; s < SLICES; ++s) { S += stats[(c*SLICES+s)*2]; Q += stats[(c*SLICES+s)*2+1]; }
    float m = S / NHW, vv = Q / NHW - m*m;
    float a = g[c] * rsqrtf(vv + 1e-5f);
    sA[c] = a; sB[c] = bta[c] - m*a;
  }
  __syncthreads();
  for (int e = threadIdx.x; e < WP*C; e += 256) {
    int wp = e / C, c = e % C;
    int w = wp - P;
    float v = 0.f;
    if (h >= 0 && h < H && w >= 0 && w < W) {
      v = in[((size_t)(b*C + c)*H + h)*W + w];
      v = fmaf(v, sA[c], sB[c]);
      v = v > 0.f ? v : 0.f;
    }
    unsigned short hh = f2bf(v);
    size_t o = ((size_t)(b*HP + hp)*WP + wp)*C + c;
    xh[o] = hh;
    xl[o] = f2bf(v - bf2f(hh));
  }
}

// ---------------- MFMA implicit-GEMM conv; SPLITK==1 writes NCHW directly ----------------
template<int CI,int HIP,int WIP,int HO,int WO,int STR,int SPLITK>
__global__ __launch_bounds__(256,4) void conv_mfma(
    const unsigned short* __restrict__ xh, const unsigned short* __restrict__ xl,
    const unsigned short* __restrict__ wh, const unsigned short* __restrict__ wl,
    float* __restrict__ part, int CO, int B) {
  constexpr int K = CI*9, NSP = HO*WO, KCH = K/SPLITK, LDA = 36;
  const int NTOT = B*NSP;
  const int m0 = blockIdx.x*64, n0 = blockIdx.y*128, ks = blockIdx.z;
  __shared__ unsigned short Ah[64*LDA], Al[64*LDA], Bh[128*LDA], Bl[128*LDA];
  const int tid = threadIdx.x, lane = tid & 63, wid = tid >> 6;
  const int wm = wid >> 1, wn = wid & 1;
  const int arow = tid >> 2, ak0 = (tid & 3)*8;
  const bool aok = (m0 + arow) < CO;
  const size_t abase = (size_t)(m0 + arow)*K;
  int brow[2], bk0[2];
  size_t bbase[2];
  #pragma unroll
  for (int i = 0; i < 2; ++i) {
    int e = tid + i*256;
    brow[i] = e >> 2; bk0[i] = (e & 3)*8;
    int nn = n0 + brow[i]; if (nn > NTOT-1) nn = NTOT-1;
    int bb = nn / NSP, sp = nn % NSP;
    int ho = sp / WO, wo = sp % WO;
    bbase[i] = ((size_t)bb*HIP + ho*STR)*WIP + wo*STR;
  }
  f32x16 acc0 = (f32x16)0.f, acc1 = (f32x16)0.f;
  const int kBeg = ks*KCH, kEnd = kBeg + KCH;
  for (int kc = kBeg; kc < kEnd; kc += 32) {
    const int kLim = (kEnd - kc) < 32 ? (kEnd - kc) : 32;
    {
      frag8 vh, vl;
      vh.v8 = (short8v)(short)0; vl.v8 = (short8v)(short)0;
      if (aok && ak0 < kLim) {
        size_t off = abase + kc + ak0;
        vh.v8 = *(const short8v*)(wh + off);
        vl.v8 = *(const short8v*)(wl + off);
      }
      int lo_ = arow*LDA + ak0;
      *(short4v*)(Ah + lo_) = vh.p.lo; *(short4v*)(Ah + lo_ + 4) = vh.p.hi;
      *(short4v*)(Al + lo_) = vl.p.lo; *(short4v*)(Al + lo_ + 4) = vl.p.hi;
    }
    #pragma unroll
    for (int i = 0; i < 2; ++i) {
      frag8 vh, vl;
      vh.v8 = (short8v)(short)0; vl.v8 = (short8v)(short)0;
      if (bk0[i] < kLim) {
        int kg = kc + bk0[i];
        int tap = kg / CI, ci0 = kg - tap*CI;
        int dh = tap / 3, dw = tap - dh*3;
        size_t off = (bbase[i] + (size_t)dh*WIP + dw)*CI + ci0;
        vh.v8 = *(const short8v*)(xh + off);
        vl.v8 = *(const short8v*)(xl + off);
      }
      int lo_ = brow[i]*LDA + bk0[i];
      *(short4v*)(Bh + lo_) = vh.p.lo; *(short4v*)(Bh + lo_ + 4) = vh.p.hi;
      *(short4v*)(Bl + lo_) = vl.p.lo; *(short4v*)(Bl + lo_ + 4) = vl.p.hi;
    }
    __syncthreads();
    #pragma unroll
    for (int kst = 0; kst < 2; ++kst) {
      const int kb = kst*16 + 8*(lane >> 5);
      const int ar = wm*32 + (lane & 31);
      frag8 ah, al;
      { int o = ar*LDA + kb;
        ah.p.lo = *(const short4v*)(Ah + o); ah.p.hi = *(const short4v*)(Ah + o + 4);
        al.p.lo = *(const short4v*)(Al + o); al.p.hi = *(const short4v*)(Al + o + 4); }
      const int br = wn*64 + (lane & 31);
      frag8 bh0, bl0, bh1, bl1;
      { int o = br*LDA + kb;
        bh0.p.lo = *(const short4v*)(Bh + o); bh0.p.hi = *(const short4v*)(Bh + o + 4);
        bl0.p.lo = *(const short4v*)(Bl + o); bl0.p.hi = *(const short4v*)(Bl + o + 4); }
      { int o = (br+32)*LDA + kb;
        bh1.p.lo = *(const short4v*)(Bh + o); bh1.p.hi = *(const short4v*)(Bh + o + 4);
        bl1.p.lo = *(const short4v*)(Bl + o); bl1.p.hi = *(const short4v*)(Bl + o + 4); }
      acc0 = __builtin_amdgcn_mfma_f32_32x32x16_bf16(ah.v8, bh0.v8, acc0, 0, 0, 0);
      acc0 = __builtin_amdgcn_mfma_f32_32x32x16_bf16(ah.v8, bl0.v8, acc0, 0, 0, 0);
      acc0 = __builtin_amdgcn_mfma_f32_32x32x16_bf16(al.v8, bh0.v8, acc0, 0, 0, 0);
      acc1 = __builtin_amdgcn_mfma_f32_32x32x16_bf16(ah.v8, bh1.v8, acc1, 0, 0, 0);
      acc1 = __builtin_amdgcn_mfma_f32_32x32x16_bf16(ah.v8, bl1.v8, acc1, 0, 0, 0);
      acc1 = __builtin_amdgcn_mfma_f32_32x32x16_bf16(al.v8, bh1.v8, acc1, 0, 0, 0);
    }
    __syncthreads();
  }
  #pragma unroll
  for (int ns = 0; ns < 2; ++ns) {
    f32x16 a = ns ? acc1 : acc0;
    #pragma unroll
    for (int r = 0; r < 16; ++r) {
      int row = (r & 3) + 8*(r >> 2) + 4*(lane >> 5);
      int m = m0 + wm*32 + row;
      int n = n0 + wn*64 + ns*32 + (lane & 31);
      if (m < CO && n < NTOT) {
        if (SPLITK == 1) {
          int b = n / NSP, sp = n % NSP;
          part[((size_t)b*CO + m)*NSP + sp] = a[r];
        } else {
          part[((size_t)ks*CO + m)*NTOT + n] = a[r];
        }
      }
    }
  }
}

// ---------------- split-K reduce (+bias, + optional fused BN partial stats) ----------------
template<int CO,int NSP,int SPLITK,bool BIAS,bool STATS>
__global__ void splitk_reduce(const float* __restrict__ part, const float* __restrict__ bias,
                              float* __restrict__ out, float* __restrict__ stats, int B) {
  const int NTOT = B*NSP;
  int i = blockIdx.x*256 + threadIdx.x;
  bool valid = i < CO*NTOT;
  float s = 0.f;
  if (valid) {
    int co = i / NTOT, n = i % NTOT;
    #pragma unroll
    for (int ks = 0; ks < SPLITK; ++ks) s += part[(size_t)(ks*CO + co)*NTOT + n];
    if (BIAS) s += bias[co];
    int b = n / NSP, sp = n % NSP;
    out[((size_t)b*CO + co)*NSP + sp] = s;
  }
  if (STATS) {
    float sum = valid ? s : 0.f, sq = valid ? s*s : 0.f;
    #pragma unroll
    for (int off = 32; off; off >>= 1) {
      sum += __shfl_down(sum, off, 64);
      sq  += __shfl_down(sq,  off, 64);
    }
    __shared__ float ls[2][4];
    int lane = threadIdx.x & 63, wv = threadIdx.x >> 6;
    if (lane == 0) { ls[0][wv] = sum; ls[1][wv] = sq; }
    __syncthreads();
    if (threadIdx.x == 0) {
      float S = 0.f, Q = 0.f;
      #pragma unroll
      for (int j = 0; j < 4; ++j) { S += ls[0][j]; Q += ls[1][j]; }
      int bpc = NTOT/256;
      int co = blockIdx.x / bpc, slice = blockIdx.x % bpc;
      stats[(co*bpc + slice)*2 + 0] = S;
      stats[(co*bpc + slice)*2 + 1] = Q;
    }
  }
}

// ---------------- BN stats ----------------
template<int C,int HW,int SLICES>
__global__ void bn_partial(const float* __restrict__ x, float* __restrict__ part, int B) {
  int c = blockIdx.x / SLICES, s = blockIdx.x % SLICES;
  int bpp = B / SLICES;
  float sum = 0.f, sq = 0.f;
  for (int b = s*bpp; b < (s+1)*bpp; ++b) {
    const float* p = x + ((size_t)b*C + c)*HW;
    for (int i = threadIdx.x; i < HW; i += blockDim.x) {
      float v = p[i]; sum += v; sq += v*v;
    }
  }
  #pragma unroll
  for (int off = 32; off; off >>= 1) {
    sum += __shfl_down(sum, off, 64);
    sq  += __shfl_down(sq,  off, 64);
  }
  __shared__ float ls[2][4];
  int lane = threadIdx.x & 63, wv = threadIdx.x >> 6;
  if (lane == 0) { ls[0][wv] = sum; ls[1][wv] = sq; }
  __syncthreads();
  if (threadIdx.x == 0) {
    float S = 0.f, Q = 0.f;
    #pragma unroll
    for (int i = 0; i < 4; ++i) { S += ls[0][i]; Q += ls[1][i]; }
    part[(c*SLICES+s)*2+0] = S; part[(c*SLICES+s)*2+1] = Q;
  }
}

// ---------------- squash primary caps in place ----------------
__global__ void squash_pc(float* __restrict__ pc, int ncaps) {
  int i = blockIdx.x*blockDim.x + threadIdx.x;
  if (i >= ncaps) return;
  float* p = pc + (size_t)i*12;
  float v[12]; float s = 0.f;
  #pragma unroll
  for (int d = 0; d < 12; ++d) { v[d] = p[d]; s += v[d]*v[d]; }
  float sc = s / ((1.f + s)*sqrtf(s + 1e-6f));
  #pragma unroll
  for (int d = 0; d < 12; ++d) p[d] = v[d]*sc;
}

// ---------------- uu gather ----------------
__global__ void uu_gather(const float* __restrict__ sq, float* __restrict__ uu, int B) {
  int idx = blockIdx.x*blockDim.x + threadIdx.x;
  int total = B*49*144*12;
  if (idx >= total) return;
  int ii = idx % 12; int t0 = idx / 12;
  int kk = t0 % 144; t0 /= 144;
  int tt = t0 % 49;  int b = t0 / 49;
  int f = tt*1728 + kk*12 + ii;
  int c = f / 441; int r = f - c*441;
  int k = r / 49;  int sp = r - k*49;
  int y = sp / 7, x = sp - y*7;
  int iy = y + k/3 - 1, ix = x + (k%3) - 1;
  float val = 0.f;
  if (iy >= 0 && iy < 7 && ix >= 0 && ix < 7)
    val = sq[((size_t)(b*192 + c)*7 + iy)*7 + ix];
  uu[idx] = val;
}

// ---------------- ConvCaps einsum: 4 o's + 16 m's per thread, ushort4 stores ----------------
// launch_bounds(192,2): VGPR budget 256 so wr[4][12] stays register-resident.
__global__ __launch_bounds__(192,2) void cc_einsum3(const float* __restrict__ uu,
                                                    const float* __restrict__ wcc,
                                                    __hip_bfloat16* __restrict__ uhat,
                                                    int row0, int nrows) {
  const int k  = blockIdx.x;
  const int m0 = blockIdx.y * 64;
  const int tid = threadIdx.x;
  const int m4 = tid / 48, oq = tid % 48;
  float wr[4][12];
  #pragma unroll
  for (int c = 0; c < 4; ++c) {
    const float4* wp4 = (const float4*)(wcc + ((size_t)k*192 + oq*4 + c)*12);
    float4 a = wp4[0], b = wp4[1], d = wp4[2];
    wr[c][0]=a.x; wr[c][1]=a.y; wr[c][2]=a.z; wr[c][3]=a.w;
    wr[c][4]=b.x; wr[c][5]=b.y; wr[c][6]=b.z; wr[c][7]=b.w;
    wr[c][8]=d.x; wr[c][9]=d.y; wr[c][10]=d.z; wr[c][11]=d.w;
  }
  int mmax = nrows - m0; if (mmax > 64) mmax = 64;
  #pragma unroll 4
  for (int mi = 0; mi < 16; ++mi) {
    int m = m4*16 + mi;
    if (m >= mmax) break;
    const float4* ar = (const float4*)(uu + ((size_t)(row0+m0+m)*144 + k)*12);
    float4 a0 = ar[0], a1 = ar[1], a2 = ar[2];
    float af[12] = {a0.x,a0.y,a0.z,a0.w,a1.x,a1.y,a1.z,a1.w,a2.x,a2.y,a2.z,a2.w};
    ushort4 pkt;
    unsigned short* pp = (unsigned short*)&pkt;
    #pragma unroll
    for (int c = 0; c < 4; ++c) {
      float acc = 0.f;
      #pragma unroll
      for (int i = 0; i < 12; ++i) acc = fmaf(wr[c][i], af[i], acc);
      pp[c] = f2bf(acc);
    }
    unsigned short* up = (unsigned short*)uhat + ((size_t)(m0+m)*144 + k)*192 + oq*4;
    *(ushort4*)up = pkt;
  }
}

// ---------------- ConvCaps routing: register stash, fused 3-pass, no-max softmax ------------
// 384 threads = 24 groups x 16 lanes. launch_bounds(384,4): proven no-spill config. FROZEN.
__global__ __launch_bounds__(384,4) void cc_route(const __hip_bfloat16* __restrict__ uhat,
                                                  float* __restrict__ u2, int rowOff) {
  const int row = blockIdx.x;
  const unsigned short* __restrict__ uh = (const unsigned short*)uhat + (size_t)row*27648;
  __shared__ float red[6][192];
  __shared__ float sraw[192];
  __shared__ float vsh[192];
  const int tid = threadIdx.x, lane = tid & 63, wv = tid >> 6;
  const int g = tid >> 4, oc = tid & 15;
  uint2 st[6][3];
  float blog[6];
  #pragma unroll
  for (int j = 0; j < 6; ++j) blog[j] = 0.f;
  float sacc[12];

  // ---- pass 0: load + stash + uniform-c sum
  #pragma unroll
  for (int d = 0; d < 12; ++d) sacc[d] = 0.f;
  #pragma unroll
  for (int j = 0; j < 6; ++j) {
    const unsigned short* up = uh + (g + 24*j)*192 + oc*12;
    uint2 q0 = *(const uint2*)up;
    uint2 q1 = *(const uint2*)(up + 4);
    uint2 q2 = *(const uint2*)(up + 8);
    st[j][0] = q0; st[j][1] = q1; st[j][2] = q2;
    sacc[0] += bf2f((unsigned short)(q0.x & 0xffff)); sacc[1] += bf2f((unsigned short)(q0.x >> 16));
    sacc[2] += bf2f((unsigned short)(q0.y & 0xffff)); sacc[3] += bf2f((unsigned short)(q0.y >> 16));
    sacc[4] += bf2f((unsigned short)(q1.x & 0xffff)); sacc[5] += bf2f((unsigned short)(q1.x >> 16));
    sacc[6] += bf2f((unsigned short)(q1.y & 0xffff)); sacc[7] += bf2f((unsigned short)(q1.y >> 16));
    sacc[8] += bf2f((unsigned short)(q2.x & 0xffff)); sacc[9] += bf2f((unsigned short)(q2.x >> 16));
    sacc[10] += bf2f((unsigned short)(q2.y & 0xffff)); sacc[11] += bf2f((unsigned short)(q2.y >> 16));
  }
  #pragma unroll
  for (int d = 0; d < 12; ++d) {
    sacc[d] += __shfl_xor(sacc[d], 16, 64);
    sacc[d] += __shfl_xor(sacc[d], 32, 64);
  }
  if (lane < 16) {
    #pragma unroll
    for (int d = 0; d < 12; ++d) red[wv][oc*12 + d] = sacc[d];
  }
  __syncthreads();
  if (tid < 192) {
    float s = (red[0][tid] + red[1][tid] + red[2][tid]
             + red[3][tid] + red[4][tid] + red[5][tid]) * 0.0625f;
    sraw[tid] = s;
  }
  __syncthreads();
  if (tid < 192) {
    int qc = tid / 12;
    float nrm = 0.f;
    #pragma unroll
    for (int d = 0; d < 12; ++d) { float v = sraw[qc*12 + d]; nrm += v*v; }
    float sc = nrm / ((1.f + nrm)*sqrtf(nrm + 1e-6f));
    vsh[tid] = sraw[tid]*sc;
  }
  __syncthreads();

  // ---- passes 1,2: all-register data, no-max softmax
  #pragma unroll
  for (int r = 1; r < 3; ++r) {
    float vq[12];
    #pragma unroll
    for (int d = 0; d < 12; ++d) vq[d] = vsh[oc*12 + d];
    #pragma unroll
    for (int d = 0; d < 12; ++d) sacc[d] = 0.f;
    #pragma unroll
    for (int j = 0; j < 6; ++j) {
      uint2 q0 = st[j][0], q1 = st[j][1], q2 = st[j][2];
      float uf[12];
      uf[0] = bf2f((unsigned short)(q0.x & 0xffff)); uf[1] = bf2f((unsigned short)(q0.x >> 16));
      uf[2] = bf2f((unsigned short)(q0.y & 0xffff)); uf[3] = bf2f((unsigned short)(q0.y >> 16));
      uf[4] = bf2f((unsigned short)(q1.x & 0xffff)); uf[5] = bf2f((unsigned short)(q1.x >> 16));
      uf[6] = bf2f((unsigned short)(q1.y & 0xffff)); uf[7] = bf2f((unsigned short)(q1.y >> 16));
      uf[8] = bf2f((unsigned short)(q2.x & 0xffff)); uf[9] = bf2f((unsigned short)(q2.x >> 16));
      uf[10] = bf2f((unsigned short)(q2.y & 0xffff)); uf[11] = bf2f((unsigned short)(q2.y >> 16));
      float dot = 0.f;
      #pragma unroll
      for (int d = 0; d < 12; ++d) dot = fmaf(vq[d], uf[d], dot);
      blog[j] += dot;
      float e = __expf(blog[j]);
      float es = e;
      #pragma unroll
      for (int off = 1; off < 16; off <<= 1) es += __shfl_xor(es, off, 16);
      float c = e / es;
      #pragma unroll
      for (int d = 0; d < 12; ++d) sacc[d] = fmaf(c, uf[d], sacc[d]);
    }
    #pragma unroll
    for (int d = 0; d < 12; ++d) {
      sacc[d] += __shfl_xor(sacc[d], 16, 64);
      sacc[d] += __shfl_xor(sacc[d], 32, 64);
    }
    if (lane < 16) {
      #pragma unroll
      for (int d = 0; d < 12; ++d) red[wv][oc*12 + d] = sacc[d];
    }
    __syncthreads();
    if (tid < 192) {
      sraw[tid] = red[0][tid] + red[1][tid] + red[2][tid]
                + red[3][tid] + red[4][tid] + red[5][tid];
    }
    __syncthreads();
    if (tid < 192) {
      int qc = tid / 12;
      float nrm = 0.f;
      #pragma unroll
      for (int d = 0; d < 12; ++d) { float v = sraw[qc*12 + d]; nrm += v*v; }
      float sc = nrm / ((1.f + nrm)*sqrtf(nrm + 1e-6f));
      vsh[tid] = sraw[tid]*sc;
    }
    __syncthreads();
  }
  if (tid < 192) u2[((size_t)(rowOff + row))*192 + tid] = vsh[tid];
}

// ---------------- Class caps einsum (bf16 output) ----------------
__global__ void class_einsum(const float* __restrict__ u2, const float* __restrict__ wcl,
                             unsigned short* __restrict__ uhat2, int B) {
  int n = blockIdx.x;
  __shared__ float u2l[64][12];
  int tid = threadIdx.x;
  for (int e = tid; e < 64*12; e += 320) {
    int b = e / 12, i = e % 12;
    u2l[b][i] = u2[(size_t)b*9408 + n*12 + i];
  }
  __syncthreads();
  int od = tid % 160, bh = tid / 160;
  int o = od >> 4, d = od & 15;
  float w[12];
  #pragma unroll
  for (int i = 0; i < 12; ++i) w[i] = wcl[(size_t)n*1920 + o*192 + d*12 + i];
  for (int b = bh*32; b < bh*32+32; ++b) {
    float acc = 0.f;
    #pragma unroll
    for (int i = 0; i < 12; ++i) acc = fmaf(w[i], u2l[b][i], acc);
    uhat2[((size_t)b*784 + n)*160 + od] = f2bf(acc);
  }
}

// ---------------- class routing: wave-local pass, no-max softmax ----------------
template<int MODE>
__global__ __launch_bounds__(256) void cls_pass(const unsigned short* __restrict__ uh2b,
                                                const float* __restrict__ vprev,
                                                float* __restrict__ b2l,
                                                float* __restrict__ cpart) {
  const int b = blockIdx.x, sl = blockIdx.y;   // sl 0..6
  const int tid = threadIdx.x, lane = tid & 63, wv = tid >> 6;
  const int nl = lane >> 4, d = lane & 15;
  float v[10];
  if (MODE != 0) {
    #pragma unroll
    for (int o = 0; o < 10; ++o) v[o] = vprev[b*160 + o*16 + d];
  }
  float sacc[10];
  #pragma unroll
  for (int o = 0; o < 10; ++o) sacc[o] = 0.f;
  for (int step = 0; step < 7; ++step) {
    const int n = sl*112 + step*16 + wv*4 + nl;
    const unsigned short* up = uh2b + ((size_t)b*784 + n)*160 + d;
    float u[10];
    #pragma unroll
    for (int o = 0; o < 10; ++o) u[o] = bf2f(up[o*16]);
    if (MODE == 0) {
      #pragma unroll
      for (int o = 0; o < 10; ++o) sacc[o] += u[o];
    } else {
      float bb[10];
      #pragma unroll
      for (int o = 0; o < 10; ++o) {
        float t = v[o]*u[o];
        #pragma unroll
        for (int off = 8; off; off >>= 1) t += __shfl_xor(t, off, 16);
        bb[o] = t;
      }
      if (MODE == 2) {
        #pragma unroll
        for (int o = 0; o < 10; ++o) bb[o] += b2l[((size_t)b*784 + n)*10 + o];
      }
      if (MODE == 1 && d < 10) b2l[((size_t)b*784 + n)*10 + d] = bb[d];
      float es = 0.f;
      #pragma unroll
      for (int o = 0; o < 10; ++o) { bb[o] = __expf(bb[o]); es += bb[o]; }
      float inv = 1.f/es;
      #pragma unroll
      for (int o = 0; o < 10; ++o) sacc[o] = fmaf(bb[o]*inv, u[o], sacc[o]);
    }
  }
  #pragma unroll
  for (int o = 0; o < 10; ++o) {
    sacc[o] += __shfl_xor(sacc[o], 16, 64);
    sacc[o] += __shfl_xor(sacc[o], 32, 64);
  }
  __shared__ float red[4][160];
  if (lane < 16) {
    #pragma unroll
    for (int o = 0; o < 10; ++o) red[wv][o*16 + d] = sacc[o];
  }
  __syncthreads();
  if (tid < 160) {
    float s = red[0][tid] + red[1][tid] + red[2][tid] + red[3][tid];
    cpart[((size_t)b*7 + sl)*160 + tid] = s;
  }
}

__global__ __launch_bounds__(160) void cls_finish(const float* __restrict__ cpart,
                                                  float* __restrict__ vout, float fac) {
  int b = blockIdx.x, od = threadIdx.x;
  float s = 0.f;
  #pragma unroll
  for (int sl = 0; sl < 7; ++sl) s += cpart[((size_t)b*7 + sl)*160 + od];
  s *= fac;
  float nrm = s*s;
  #pragma unroll
  for (int off = 8; off; off >>= 1) nrm += __shfl_xor(nrm, off, 16);
  float sc = nrm / ((1.f + nrm)*sqrtf(nrm + 1e-6f));
  vout[(size_t)b*160 + od] = s*sc;
}

// ---------------- host launch ----------------
extern "C" void kernel_launch(void* const* d_in, const int* in_sizes, int n_in,
                              void* d_out, int out_size, void* d_ws, size_t ws_size,
                              hipStream_t stream) {
  const float* images = (const float*)d_in[0];
  const float* w1  = (const float*)d_in[1];
  const float* g1  = (const float*)d_in[2];
  const float* b1  = (const float*)d_in[3];
  const float* w2  = (const float*)d_in[4];
  const float* g2  = (const float*)d_in[5];
  const float* b2  = (const float*)d_in[6];
  const float* w3  = (const float*)d_in[7];
  const float* g3  = (const float*)d_in[8];
  const float* b3  = (const float*)d_in[9];
  const float* wp  = (const float*)d_in[10];
  const float* bp  = (const float*)d_in[11];
  const float* wcc = (const float*)d_in[12];
  const float* wcl = (const float*)d_in[13];
  float* out = (float*)d_out;
  float* ws  = (float*)d_ws;

  // persistent regions (float offsets)
  float* t1    = ws + 0;            // 3,145,728
  float* t2    = ws + 3145728;      // 1,572,864
  float* t3    = ws + 4718592;      // 3,145,728
  float* pc    = ws + 7864320;      //   602,112
  float* uu    = ws + 8466432;      // 5,419,008
  float* u2b   = ws + 13885440;     //   602,112
  unsigned short* uh2b = (unsigned short*)(ws + 14487552);  // 8,028,160 ushorts
  float* b2l   = ws + 22515712;     //   501,760
  float* scrC  = ws + 23017472;     //   501,760 (BN stats during convs, cpart during class)
  float* v2    = ws + 23519232;     //    10,240
  float* spart = ws + 23529472;     //     3,072
  float* U     = ws + 23533312;     // arena, 10,838,016 f32 (conv transients)
  __hip_bfloat16* uhc = (__hip_bfloat16*)(ws + 34371328);   // 43,352,064 bf16 (one 32-img chunk)

  // split/reordered weights live in dead `uu` region (dead until uu_gather)
  unsigned short* wh2 = (unsigned short*)(uu + 0);
  unsigned short* wl2 = (unsigned short*)(uu + 20736);
  unsigned short* wh3 = (unsigned short*)(uu + 41472);
  unsigned short* wl3 = (unsigned short*)(uu + 124416);
  unsigned short* whp = (unsigned short*)(uu + 207360);
  unsigned short* wlp = (unsigned short*)(uu + 373248);

  // phase transients in the U arena
  unsigned short* x2h = (unsigned short*)(U + 0);
  unsigned short* x2l = (unsigned short*)(U + 1775616);
  float*          part2 = U + 3551232;                    // 3x96x16384
  unsigned short* x3h = (unsigned short*)(U + 0);
  unsigned short* x3l = (unsigned short*)(U + 995328);
  unsigned short* xph = (unsigned short*)(U + 0);
  unsigned short* xpl = (unsigned short*)(U + 1572864);
  float*          partp = U + 3145728;                    // 8x192x3136

  const int B = 64;

  // merged weight splits
  split_w_all<<<2106,256,0,stream>>>(w2, w3, wp, wh2, wl2, wh3, wl3, whp, wlp);

  // conv1 + BN1 stats
  conv1_fused<<<2048,192,0,stream>>>(images, w1, t1);
  bn_partial<48,1024,8><<<48*8,256,0,stream>>>(t1, spart, B);

  // conv2: fused BN1-final+affine+ReLU+split (with halos), MFMA split-K=3, reduce+stats
  bn_split_nhwc2<48,32,32,1,8><<<64*34,256,0,stream>>>(t1, spart, g1, b1, x2h, x2l, 65536);
  conv_mfma<48,34,34,16,16,2,3><<<dim3(2,128,3),256,0,stream>>>(x2h, x2l, wh2, wl2, part2, 96, B);
  splitk_reduce<96,256,3,false,true><<<6144,256,0,stream>>>(part2, nullptr, t2, scrC, B);

  // conv3: fused BN2-final in split pass; direct NCHW write, stats via bn_partial
  bn_split_nhwc2<96,16,16,1,64><<<64*18,256,0,stream>>>(t2, scrC, g2, b2, x3h, x3l, 16384);
  conv_mfma<96,18,18,16,16,1,1><<<dim3(3,128,1),256,0,stream>>>(x3h, x3l, wh3, wl3, t3, 192, B);
  bn_partial<192,256,8><<<192*8,256,0,stream>>>(t3, spart, B);

  // primary caps conv (fused BN3-final in split pass) + bias, then squash
  bn_split_nhwc2<192,16,16,0,8><<<64*16,256,0,stream>>>(t3, spart, g3, b3, xph, xpl, 16384);
  conv_mfma<192,16,16,7,7,2,8><<<dim3(3,25,8),256,0,stream>>>(xph, xpl, whp, wlp, partp, 192, B);
  splitk_reduce<192,49,8,true,false><<<2352,256,0,stream>>>(partp, bp, pc, nullptr, B);
  squash_pc<<<196,256,0,stream>>>(pc, 50176);

  // uu gather
  uu_gather<<<21168,256,0,stream>>>(pc, uu, B);
  // ConvCaps einsum (wide stores, full VGPR budget) + register-stash fused routing
  for (int cb = 0; cb < 2; ++cb) {
    cc_einsum3<<<dim3(144,25),192,0,stream>>>(uu, wcc, uhc, cb*1568, 1568);
    cc_route<<<1568,384,0,stream>>>(uhc, u2b, cb*1568);
  }
  // Class caps einsum (bf16) + wave-local routing
  class_einsum<<<784,320,0,stream>>>(u2b, wcl, uh2b, B);
  cls_pass<0><<<dim3(64,7),256,0,stream>>>(uh2b, v2, b2l, scrC);
  cls_finish<<<64,160,0,stream>>>(scrC, v2, 0.1f);
  cls_pass<1><<<dim3(64,7),256,0,stream>>>(uh2b, v2, b2l, scrC);
  cls_finish<<<64,160,0,stream>>>(scrC, v2, 1.0f);
  cls_pass<2><<<dim3(64,7),256,0,stream>>>(uh2b, v2, b2l, scrC);
  cls_finish<<<64,160,0,stream>>>(scrC, out, 1.0f);
  (void)in_sizes; (void)n_in; (void)out_size; (void)ws_size;
}

// Round 17
// 354.786 us; speedup vs baseline: 1.7670x; 1.0453x over previous
//
#include <hip/hip_runtime.h>
#include <hip/hip_bf16.h>

typedef __attribute__((ext_vector_type(4))) short short4v;
typedef __attribute__((ext_vector_type(8))) short short8v;
typedef __attribute__((ext_vector_type(16))) float f32x16;

union frag8 { short8v v8; struct { short4v lo, hi; } p; };

__device__ __forceinline__ unsigned short f2bf(float v) {
  unsigned u = __float_as_uint(v);
  unsigned r = u + 0x7fffu + ((u >> 16) & 1u);
  return (unsigned short)(r >> 16);
}
__device__ __forceinline__ float bf2f(unsigned short h) {
  return __uint_as_float(((unsigned)h) << 16);
}

// ---------------- conv1: one block per (b,h), LDS input slab, weights in regs ----------------
__global__ __launch_bounds__(192) void conv1_fused(const float* __restrict__ images,
                                                   const float* __restrict__ w1,
                                                   float* __restrict__ out) {
  int b = blockIdx.x >> 5, h = blockIdx.x & 31;
  __shared__ __align__(16) float lin[3][3][36];
  int tid = threadIdx.x;
  for (int e = tid; e < 324; e += 192) {
    int ci = e / 108, rem = e % 108, ki = rem / 36, wi = rem % 36;
    int row = h + ki - 1, col = wi - 1;
    float v = 0.f;
    if (row >= 0 && row < 32 && col >= 0 && col < 32)
      v = images[((size_t)(b*3 + ci)*32 + row)*32 + col];
    lin[ci][ki][wi] = v;
  }
  int co = tid >> 2, ws = tid & 3;
  float wr[27];
  #pragma unroll
  for (int j = 0; j < 27; ++j) wr[j] = w1[co*27 + j];
  __syncthreads();
  float o[8];
  #pragma unroll
  for (int j = 0; j < 8; ++j) o[j] = 0.f;
  #pragma unroll
  for (int ci = 0; ci < 3; ++ci)
    #pragma unroll
    for (int ki = 0; ki < 3; ++ki) {
      float4 q0 = *(const float4*)&lin[ci][ki][ws*8];
      float4 q1 = *(const float4*)&lin[ci][ki][ws*8+4];
      float4 q2 = *(const float4*)&lin[ci][ki][ws*8+8];
      float r[12] = {q0.x,q0.y,q0.z,q0.w,q1.x,q1.y,q1.z,q1.w,q2.x,q2.y,q2.z,q2.w};
      #pragma unroll
      for (int kj = 0; kj < 3; ++kj) {
        float wv = wr[(ci*3+ki)*3+kj];
        #pragma unroll
        for (int j = 0; j < 8; ++j) o[j] = fmaf(r[j+kj], wv, o[j]);
      }
    }
  float* dst = out + (((size_t)(b*48+co)*32 + h)*32 + ws*8);
  *(float4*)dst       = make_float4(o[0],o[1],o[2],o[3]);
  *(float4*)(dst + 4) = make_float4(o[4],o[5],o[6],o[7]);
}

// ---------------- merged weight split+reorder for conv2/conv3/primary ----------------
__device__ __forceinline__ void split_one(const float* w, unsigned short* wh,
                                          unsigned short* wl, int CI, int i) {
  int K = CI*9;
  int co = i / K, rem = i % K, tap = rem / CI, ci = rem % CI;
  float v = w[(co*CI + ci)*9 + tap];
  unsigned short h = f2bf(v);
  wh[i] = h;
  wl[i] = f2bf(v - bf2f(h));
}
__global__ void split_w_all(const float* __restrict__ w2, const float* __restrict__ w3,
                            const float* __restrict__ wp,
                            unsigned short* wh2, unsigned short* wl2,
                            unsigned short* wh3, unsigned short* wl3,
                            unsigned short* whp, unsigned short* wlp) {
  int i = blockIdx.x*256 + threadIdx.x;
  if (i < 41472) split_one(w2, wh2, wl2, 48, i);
  else if (i < 207360) split_one(w3, wh3, wl3, 96, i - 41472);
  else if (i < 539136) split_one(wp, whp, wlp, 192, i - 207360);
}

// ------- BN finalize (in-block from raw stats) + affine + ReLU + split to padded NHWC -------
template<int C,int H,int W,int P,int SLICES>
__global__ void bn_split_nhwc2(const float* __restrict__ in, const float* __restrict__ stats,
                               const float* __restrict__ g, const float* __restrict__ bta,
                               unsigned short* __restrict__ xh, unsigned short* __restrict__ xl,
                               int NHW) {
  constexpr int HP = H + 2*P, WP = W + 2*P;
  __shared__ float sA[C], sB[C];
  int b = blockIdx.x / HP, hp = blockIdx.x % HP;
  int h = hp - P;
  for (int c = threadIdx.x; c < C; c += 256) {
    float S = 0.f, Q = 0.f;
    #pragma unroll 4
    for (int s = 0; s < SLICES; ++s) { S += stats[(c*SLICES+s)*2]; Q += stats[(c*SLICES+s)*2+1]; }
    float m = S / NHW, vv = Q / NHW - m*m;
    float a = g[c] * rsqrtf(vv + 1e-5f);
    sA[c] = a; sB[c] = bta[c] - m*a;
  }
  __syncthreads();
  for (int e = threadIdx.x; e < WP*C; e += 256) {
    int wp = e / C, c = e % C;
    int w = wp - P;
    float v = 0.f;
    if (h >= 0 && h < H && w >= 0 && w < W) {
      v = in[((size_t)(b*C + c)*H + h)*W + w];
      v = fmaf(v, sA[c], sB[c]);
      v = v > 0.f ? v : 0.f;
    }
    unsigned short hh = f2bf(v);
    size_t o = ((size_t)(b*HP + hp)*WP + wp)*C + c;
    xh[o] = hh;
    xl[o] = f2bf(v - bf2f(hh));
  }
}

// ---------------- MFMA implicit-GEMM conv; SPLITK==1 writes NCHW directly ----------------
template<int CI,int HIP,int WIP,int HO,int WO,int STR,int SPLITK>
__global__ __launch_bounds__(256,4) void conv_mfma(
    const unsigned short* __restrict__ xh, const unsigned short* __restrict__ xl,
    const unsigned short* __restrict__ wh, const unsigned short* __restrict__ wl,
    float* __restrict__ part, int CO, int B) {
  constexpr int K = CI*9, NSP = HO*WO, KCH = K/SPLITK, LDA = 36;
  const int NTOT = B*NSP;
  const int m0 = blockIdx.x*64, n0 = blockIdx.y*128, ks = blockIdx.z;
  __shared__ unsigned short Ah[64*LDA], Al[64*LDA], Bh[128*LDA], Bl[128*LDA];
  const int tid = threadIdx.x, lane = tid & 63, wid = tid >> 6;
  const int wm = wid >> 1, wn = wid & 1;
  const int arow = tid >> 2, ak0 = (tid & 3)*8;
  const bool aok = (m0 + arow) < CO;
  const size_t abase = (size_t)(m0 + arow)*K;
  int brow[2], bk0[2];
  size_t bbase[2];
  #pragma unroll
  for (int i = 0; i < 2; ++i) {
    int e = tid + i*256;
    brow[i] = e >> 2; bk0[i] = (e & 3)*8;
    int nn = n0 + brow[i]; if (nn > NTOT-1) nn = NTOT-1;
    int bb = nn / NSP, sp = nn % NSP;
    int ho = sp / WO, wo = sp % WO;
    bbase[i] = ((size_t)bb*HIP + ho*STR)*WIP + wo*STR;
  }
  f32x16 acc0 = (f32x16)0.f, acc1 = (f32x16)0.f;
  const int kBeg = ks*KCH, kEnd = kBeg + KCH;
  for (int kc = kBeg; kc < kEnd; kc += 32) {
    const int kLim = (kEnd - kc) < 32 ? (kEnd - kc) : 32;
    {
      frag8 vh, vl;
      vh.v8 = (short8v)(short)0; vl.v8 = (short8v)(short)0;
      if (aok && ak0 < kLim) {
        size_t off = abase + kc + ak0;
        vh.v8 = *(const short8v*)(wh + off);
        vl.v8 = *(const short8v*)(wl + off);
      }
      int lo_ = arow*LDA + ak0;
      *(short4v*)(Ah + lo_) = vh.p.lo; *(short4v*)(Ah + lo_ + 4) = vh.p.hi;
      *(short4v*)(Al + lo_) = vl.p.lo; *(short4v*)(Al + lo_ + 4) = vl.p.hi;
    }
    #pragma unroll
    for (int i = 0; i < 2; ++i) {
      frag8 vh, vl;
      vh.v8 = (short8v)(short)0; vl.v8 = (short8v)(short)0;
      if (bk0[i] < kLim) {
        int kg = kc + bk0[i];
        int tap = kg / CI, ci0 = kg - tap*CI;
        int dh = tap / 3, dw = tap - dh*3;
        size_t off = (bbase[i] + (size_t)dh*WIP + dw)*CI + ci0;
        vh.v8 = *(const short8v*)(xh + off);
        vl.v8 = *(const short8v*)(xl + off);
      }
      int lo_ = brow[i]*LDA + bk0[i];
      *(short4v*)(Bh + lo_) = vh.p.lo; *(short4v*)(Bh + lo_ + 4) = vh.p.hi;
      *(short4v*)(Bl + lo_) = vl.p.lo; *(short4v*)(Bl + lo_ + 4) = vl.p.hi;
    }
    __syncthreads();
    #pragma unroll
    for (int kst = 0; kst < 2; ++kst) {
      const int kb = kst*16 + 8*(lane >> 5);
      const int ar = wm*32 + (lane & 31);
      frag8 ah, al;
      { int o = ar*LDA + kb;
        ah.p.lo = *(const short4v*)(Ah + o); ah.p.hi = *(const short4v*)(Ah + o + 4);
        al.p.lo = *(const short4v*)(Al + o); al.p.hi = *(const short4v*)(Al + o + 4); }
      const int br = wn*64 + (lane & 31);
      frag8 bh0, bl0, bh1, bl1;
      { int o = br*LDA + kb;
        bh0.p.lo = *(const short4v*)(Bh + o); bh0.p.hi = *(const short4v*)(Bh + o + 4);
        bl0.p.lo = *(const short4v*)(Bl + o); bl0.p.hi = *(const short4v*)(Bl + o + 4); }
      { int o = (br+32)*LDA + kb;
        bh1.p.lo = *(const short4v*)(Bh + o); bh1.p.hi = *(const short4v*)(Bh + o + 4);
        bl1.p.lo = *(const short4v*)(Bl + o); bl1.p.hi = *(const short4v*)(Bl + o + 4); }
      acc0 = __builtin_amdgcn_mfma_f32_32x32x16_bf16(ah.v8, bh0.v8, acc0, 0, 0, 0);
      acc0 = __builtin_amdgcn_mfma_f32_32x32x16_bf16(ah.v8, bl0.v8, acc0, 0, 0, 0);
      acc0 = __builtin_amdgcn_mfma_f32_32x32x16_bf16(al.v8, bh0.v8, acc0, 0, 0, 0);
      acc1 = __builtin_amdgcn_mfma_f32_32x32x16_bf16(ah.v8, bh1.v8, acc1, 0, 0, 0);
      acc1 = __builtin_amdgcn_mfma_f32_32x32x16_bf16(ah.v8, bl1.v8, acc1, 0, 0, 0);
      acc1 = __builtin_amdgcn_mfma_f32_32x32x16_bf16(al.v8, bh1.v8, acc1, 0, 0, 0);
    }
    __syncthreads();
  }
  #pragma unroll
  for (int ns = 0; ns < 2; ++ns) {
    f32x16 a = ns ? acc1 : acc0;
    #pragma unroll
    for (int r = 0; r < 16; ++r) {
      int row = (r & 3) + 8*(r >> 2) + 4*(lane >> 5);
      int m = m0 + wm*32 + row;
      int n = n0 + wn*64 + ns*32 + (lane & 31);
      if (m < CO && n < NTOT) {
        if (SPLITK == 1) {
          int b = n / NSP, sp = n % NSP;
          part[((size_t)b*CO + m)*NSP + sp] = a[r];
        } else {
          part[((size_t)ks*CO + m)*NTOT + n] = a[r];
        }
      }
    }
  }
}

// ---------------- split-K reduce (+bias, + optional fused BN partial stats) ----------------
template<int CO,int NSP,int SPLITK,bool BIAS,bool STATS>
__global__ void splitk_reduce(const float* __restrict__ part, const float* __restrict__ bias,
                              float* __restrict__ out, float* __restrict__ stats, int B) {
  const int NTOT = B*NSP;
  int i = blockIdx.x*256 + threadIdx.x;
  bool valid = i < CO*NTOT;
  float s = 0.f;
  if (valid) {
    int co = i / NTOT, n = i % NTOT;
    #pragma unroll
    for (int ks = 0; ks < SPLITK; ++ks) s += part[(size_t)(ks*CO + co)*NTOT + n];
    if (BIAS) s += bias[co];
    int b = n / NSP, sp = n % NSP;
    out[((size_t)b*CO + co)*NSP + sp] = s;
  }
  if (STATS) {
    float sum = valid ? s : 0.f, sq = valid ? s*s : 0.f;
    #pragma unroll
    for (int off = 32; off; off >>= 1) {
      sum += __shfl_down(sum, off, 64);
      sq  += __shfl_down(sq,  off, 64);
    }
    __shared__ float ls[2][4];
    int lane = threadIdx.x & 63, wv = threadIdx.x >> 6;
    if (lane == 0) { ls[0][wv] = sum; ls[1][wv] = sq; }
    __syncthreads();
    if (threadIdx.x == 0) {
      float S = 0.f, Q = 0.f;
      #pragma unroll
      for (int j = 0; j < 4; ++j) { S += ls[0][j]; Q += ls[1][j]; }
      int bpc = NTOT/256;
      int co = blockIdx.x / bpc, slice = blockIdx.x % bpc;
      stats[(co*bpc + slice)*2 + 0] = S;
      stats[(co*bpc + slice)*2 + 1] = Q;
    }
  }
}

// ---------------- BN stats ----------------
template<int C,int HW,int SLICES>
__global__ void bn_partial(const float* __restrict__ x, float* __restrict__ part, int B) {
  int c = blockIdx.x / SLICES, s = blockIdx.x % SLICES;
  int bpp = B / SLICES;
  float sum = 0.f, sq = 0.f;
  for (int b = s*bpp; b < (s+1)*bpp; ++b) {
    const float* p = x + ((size_t)b*C + c)*HW;
    for (int i = threadIdx.x; i < HW; i += blockDim.x) {
      float v = p[i]; sum += v; sq += v*v;
    }
  }
  #pragma unroll
  for (int off = 32; off; off >>= 1) {
    sum += __shfl_down(sum, off, 64);
    sq  += __shfl_down(sq,  off, 64);
  }
  __shared__ float ls[2][4];
  int lane = threadIdx.x & 63, wv = threadIdx.x >> 6;
  if (lane == 0) { ls[0][wv] = sum; ls[1][wv] = sq; }
  __syncthreads();
  if (threadIdx.x == 0) {
    float S = 0.f, Q = 0.f;
    #pragma unroll
    for (int i = 0; i < 4; ++i) { S += ls[0][i]; Q += ls[1][i]; }
    part[(c*SLICES+s)*2+0] = S; part[(c*SLICES+s)*2+1] = Q;
  }
}

// ---------------- squash primary caps in place ----------------
__global__ void squash_pc(float* __restrict__ pc, int ncaps) {
  int i = blockIdx.x*blockDim.x + threadIdx.x;
  if (i >= ncaps) return;
  float* p = pc + (size_t)i*12;
  float v[12]; float s = 0.f;
  #pragma unroll
  for (int d = 0; d < 12; ++d) { v[d] = p[d]; s += v[d]*v[d]; }
  float sc = s / ((1.f + s)*sqrtf(s + 1e-6f));
  #pragma unroll
  for (int d = 0; d < 12; ++d) p[d] = v[d]*sc;
}

// ---------------- uu gather ----------------
__global__ void uu_gather(const float* __restrict__ sq, float* __restrict__ uu, int B) {
  int idx = blockIdx.x*blockDim.x + threadIdx.x;
  int total = B*49*144*12;
  if (idx >= total) return;
  int ii = idx % 12; int t0 = idx / 12;
  int kk = t0 % 144; t0 /= 144;
  int tt = t0 % 49;  int b = t0 / 49;
  int f = tt*1728 + kk*12 + ii;
  int c = f / 441; int r = f - c*441;
  int k = r / 49;  int sp = r - k*49;
  int y = sp / 7, x = sp - y*7;
  int iy = y + k/3 - 1, ix = x + (k%3) - 1;
  float val = 0.f;
  if (iy >= 0 && iy < 7 && ix >= 0 && ix < 7)
    val = sq[((size_t)(b*192 + c)*7 + iy)*7 + ix];
  uu[idx] = val;
}

// ---- ConvCaps einsum v5: o-per-thread (weights resident, broadcast uu reads)
//      + 4-row LDS transpose staging for ushort4 stores.
__global__ __launch_bounds__(192) void cc_einsum5(const float* __restrict__ uu,
                                                  const float* __restrict__ wcc,
                                                  __hip_bfloat16* __restrict__ uhat,
                                                  int row0, int nrows) {
  const int k = blockIdx.x;
  const int m0 = blockIdx.y * 64;
  const int o = threadIdx.x;
  __shared__ __align__(16) unsigned short stg[4][192];
  const float4* wp4 = (const float4*)(wcc + ((size_t)k*192 + o)*12);
  float4 w0 = wp4[0], w1 = wp4[1], w2 = wp4[2];
  int mmax = nrows - m0; if (mmax > 64) mmax = 64;   // 64 or 32: divisible by 4
  for (int mb = 0; mb < mmax; mb += 4) {
    #pragma unroll
    for (int mi = 0; mi < 4; ++mi) {
      int m = mb + mi;
      const float4* ar = (const float4*)(uu + ((size_t)(row0+m0+m)*144 + k)*12);
      float4 a0 = ar[0], a1 = ar[1], a2 = ar[2];
      float acc = a0.x*w0.x + a0.y*w0.y + a0.z*w0.z + a0.w*w0.w
                + a1.x*w1.x + a1.y*w1.y + a1.z*w1.z + a1.w*w1.w
                + a2.x*w2.x + a2.y*w2.y + a2.z*w2.z + a2.w*w2.w;
      stg[mi][o] = f2bf(acc);
    }
    __syncthreads();
    {
      int mi = o / 48, oq = o % 48;
      int m = mb + mi;
      ushort4 pkt = *(const ushort4*)&stg[mi][oq*4];
      unsigned short* up = (unsigned short*)uhat + ((size_t)(m0+m)*144 + k)*192 + oq*4;
      *(ushort4*)up = pkt;
    }
    __syncthreads();
  }
}

// ---------------- ConvCaps routing: register stash, fused 3-pass, no-max softmax ------------
// 384 threads = 24 groups x 16 lanes. launch_bounds(384,4): proven no-spill config. FROZEN.
__global__ __launch_bounds__(384,4) void cc_route(const __hip_bfloat16* __restrict__ uhat,
                                                  float* __restrict__ u2, int rowOff) {
  const int row = blockIdx.x;
  const unsigned short* __restrict__ uh = (const unsigned short*)uhat + (size_t)row*27648;
  __shared__ float red[6][192];
  __shared__ float sraw[192];
  __shared__ float vsh[192];
  const int tid = threadIdx.x, lane = tid & 63, wv = tid >> 6;
  const int g = tid >> 4, oc = tid & 15;
  uint2 st[6][3];
  float blog[6];
  #pragma unroll
  for (int j = 0; j < 6; ++j) blog[j] = 0.f;
  float sacc[12];

  // ---- pass 0: load + stash + uniform-c sum
  #pragma unroll
  for (int d = 0; d < 12; ++d) sacc[d] = 0.f;
  #pragma unroll
  for (int j = 0; j < 6; ++j) {
    const unsigned short* up = uh + (g + 24*j)*192 + oc*12;
    uint2 q0 = *(const uint2*)up;
    uint2 q1 = *(const uint2*)(up + 4);
    uint2 q2 = *(const uint2*)(up + 8);
    st[j][0] = q0; st[j][1] = q1; st[j][2] = q2;
    sacc[0] += bf2f((unsigned short)(q0.x & 0xffff)); sacc[1] += bf2f((unsigned short)(q0.x >> 16));
    sacc[2] += bf2f((unsigned short)(q0.y & 0xffff)); sacc[3] += bf2f((unsigned short)(q0.y >> 16));
    sacc[4] += bf2f((unsigned short)(q1.x & 0xffff)); sacc[5] += bf2f((unsigned short)(q1.x >> 16));
    sacc[6] += bf2f((unsigned short)(q1.y & 0xffff)); sacc[7] += bf2f((unsigned short)(q1.y >> 16));
    sacc[8] += bf2f((unsigned short)(q2.x & 0xffff)); sacc[9] += bf2f((unsigned short)(q2.x >> 16));
    sacc[10] += bf2f((unsigned short)(q2.y & 0xffff)); sacc[11] += bf2f((unsigned short)(q2.y >> 16));
  }
  #pragma unroll
  for (int d = 0; d < 12; ++d) {
    sacc[d] += __shfl_xor(sacc[d], 16, 64);
    sacc[d] += __shfl_xor(sacc[d], 32, 64);
  }
  if (lane < 16) {
    #pragma unroll
    for (int d = 0; d < 12; ++d) red[wv][oc*12 + d] = sacc[d];
  }
  __syncthreads();
  if (tid < 192) {
    float s = (red[0][tid] + red[1][tid] + red[2][tid]
             + red[3][tid] + red[4][tid] + red[5][tid]) * 0.0625f;
    sraw[tid] = s;
  }
  __syncthreads();
  if (tid < 192) {
    int qc = tid / 12;
    float nrm = 0.f;
    #pragma unroll
    for (int d = 0; d < 12; ++d) { float v = sraw[qc*12 + d]; nrm += v*v; }
    float sc = nrm / ((1.f + nrm)*sqrtf(nrm + 1e-6f));
    vsh[tid] = sraw[tid]*sc;
  }
  __syncthreads();

  // ---- passes 1,2: all-register data, no-max softmax
  #pragma unroll
  for (int r = 1; r < 3; ++r) {
    float vq[12];
    #pragma unroll
    for (int d = 0; d < 12; ++d) vq[d] = vsh[oc*12 + d];
    #pragma unroll
    for (int d = 0; d < 12; ++d) sacc[d] = 0.f;
    #pragma unroll
    for (int j = 0; j < 6; ++j) {
      uint2 q0 = st[j][0], q1 = st[j][1], q2 = st[j][2];
      float uf[12];
      uf[0] = bf2f((unsigned short)(q0.x & 0xffff)); uf[1] = bf2f((unsigned short)(q0.x >> 16));
      uf[2] = bf2f((unsigned short)(q0.y & 0xffff)); uf[3] = bf2f((unsigned short)(q0.y >> 16));
      uf[4] = bf2f((unsigned short)(q1.x & 0xffff)); uf[5] = bf2f((unsigned short)(q1.x >> 16));
      uf[6] = bf2f((unsigned short)(q1.y & 0xffff)); uf[7] = bf2f((unsigned short)(q1.y >> 16));
      uf[8] = bf2f((unsigned short)(q2.x & 0xffff)); uf[9] = bf2f((unsigned short)(q2.x >> 16));
      uf[10] = bf2f((unsigned short)(q2.y & 0xffff)); uf[11] = bf2f((unsigned short)(q2.y >> 16));
      float dot = 0.f;
      #pragma unroll
      for (int d = 0; d < 12; ++d) dot = fmaf(vq[d], uf[d], dot);
      blog[j] += dot;
      float e = __expf(blog[j]);
      float es = e;
      #pragma unroll
      for (int off = 1; off < 16; off <<= 1) es += __shfl_xor(es, off, 16);
      float c = e / es;
      #pragma unroll
      for (int d = 0; d < 12; ++d) sacc[d] = fmaf(c, uf[d], sacc[d]);
    }
    #pragma unroll
    for (int d = 0; d < 12; ++d) {
      sacc[d] += __shfl_xor(sacc[d], 16, 64);
      sacc[d] += __shfl_xor(sacc[d], 32, 64);
    }
    if (lane < 16) {
      #pragma unroll
      for (int d = 0; d < 12; ++d) red[wv][oc*12 + d] = sacc[d];
    }
    __syncthreads();
    if (tid < 192) {
      sraw[tid] = red[0][tid] + red[1][tid] + red[2][tid]
                + red[3][tid] + red[4][tid] + red[5][tid];
    }
    __syncthreads();
    if (tid < 192) {
      int qc = tid / 12;
      float nrm = 0.f;
      #pragma unroll
      for (int d = 0; d < 12; ++d) { float v = sraw[qc*12 + d]; nrm += v*v; }
      float sc = nrm / ((1.f + nrm)*sqrtf(nrm + 1e-6f));
      vsh[tid] = sraw[tid]*sc;
    }
    __syncthreads();
  }
  if (tid < 192) u2[((size_t)(rowOff + row))*192 + tid] = vsh[tid];
}

// ---------------- Class caps einsum (bf16 output) ----------------
__global__ void class_einsum(const float* __restrict__ u2, const float* __restrict__ wcl,
                             unsigned short* __restrict__ uhat2, int B) {
  int n = blockIdx.x;
  __shared__ float u2l[64][12];
  int tid = threadIdx.x;
  for (int e = tid; e < 64*12; e += 320) {
    int b = e / 12, i = e % 12;
    u2l[b][i] = u2[(size_t)b*9408 + n*12 + i];
  }
  __syncthreads();
  int od = tid % 160, bh = tid / 160;
  int o = od >> 4, d = od & 15;
  float w[12];
  #pragma unroll
  for (int i = 0; i < 12; ++i) w[i] = wcl[(size_t)n*1920 + o*192 + d*12 + i];
  for (int b = bh*32; b < bh*32+32; ++b) {
    float acc = 0.f;
    #pragma unroll
    for (int i = 0; i < 12; ++i) acc = fmaf(w[i], u2l[b][i], acc);
    uhat2[((size_t)b*784 + n)*160 + od] = f2bf(acc);
  }
}

// ---------------- class routing: wave-local pass, no-max softmax ----------------
template<int MODE>
__global__ __launch_bounds__(256) void cls_pass(const unsigned short* __restrict__ uh2b,
                                                const float* __restrict__ vprev,
                                                float* __restrict__ b2l,
                                                float* __restrict__ cpart) {
  const int b = blockIdx.x, sl = blockIdx.y;   // sl 0..6
  const int tid = threadIdx.x, lane = tid & 63, wv = tid >> 6;
  const int nl = lane >> 4, d = lane & 15;
  float v[10];
  if (MODE != 0) {
    #pragma unroll
    for (int o = 0; o < 10; ++o) v[o] = vprev[b*160 + o*16 + d];
  }
  float sacc[10];
  #pragma unroll
  for (int o = 0; o < 10; ++o) sacc[o] = 0.f;
  for (int step = 0; step < 7; ++step) {
    const int n = sl*112 + step*16 + wv*4 + nl;
    const unsigned short* up = uh2b + ((size_t)b*784 + n)*160 + d;
    float u[10];
    #pragma unroll
    for (int o = 0; o < 10; ++o) u[o] = bf2f(up[o*16]);
    if (MODE == 0) {
      #pragma unroll
      for (int o = 0; o < 10; ++o) sacc[o] += u[o];
    } else {
      float bb[10];
      #pragma unroll
      for (int o = 0; o < 10; ++o) {
        float t = v[o]*u[o];
        #pragma unroll
        for (int off = 8; off; off >>= 1) t += __shfl_xor(t, off, 16);
        bb[o] = t;
      }
      if (MODE == 2) {
        #pragma unroll
        for (int o = 0; o < 10; ++o) bb[o] += b2l[((size_t)b*784 + n)*10 + o];
      }
      if (MODE == 1 && d < 10) b2l[((size_t)b*784 + n)*10 + d] = bb[d];
      float es = 0.f;
      #pragma unroll
      for (int o = 0; o < 10; ++o) { bb[o] = __expf(bb[o]); es += bb[o]; }
      float inv = 1.f/es;
      #pragma unroll
      for (int o = 0; o < 10; ++o) sacc[o] = fmaf(bb[o]*inv, u[o], sacc[o]);
    }
  }
  #pragma unroll
  for (int o = 0; o < 10; ++o) {
    sacc[o] += __shfl_xor(sacc[o], 16, 64);
    sacc[o] += __shfl_xor(sacc[o], 32, 64);
  }
  __shared__ float red[4][160];
  if (lane < 16) {
    #pragma unroll
    for (int o = 0; o < 10; ++o) red[wv][o*16 + d] = sacc[o];
  }
  __syncthreads();
  if (tid < 160) {
    float s = red[0][tid] + red[1][tid] + red[2][tid] + red[3][tid];
    cpart[((size_t)b*7 + sl)*160 + tid] = s;
  }
}

__global__ __launch_bounds__(160) void cls_finish(const float* __restrict__ cpart,
                                                  float* __restrict__ vout, float fac) {
  int b = blockIdx.x, od = threadIdx.x;
  float s = 0.f;
  #pragma unroll
  for (int sl = 0; sl < 7; ++sl) s += cpart[((size_t)b*7 + sl)*160 + od];
  s *= fac;
  float nrm = s*s;
  #pragma unroll
  for (int off = 8; off; off >>= 1) nrm += __shfl_xor(nrm, off, 16);
  float sc = nrm / ((1.f + nrm)*sqrtf(nrm + 1e-6f));
  vout[(size_t)b*160 + od] = s*sc;
}

// ---------------- host launch ----------------
extern "C" void kernel_launch(void* const* d_in, const int* in_sizes, int n_in,
                              void* d_out, int out_size, void* d_ws, size_t ws_size,
                              hipStream_t stream) {
  const float* images = (const float*)d_in[0];
  const float* w1  = (const float*)d_in[1];
  const float* g1  = (const float*)d_in[2];
  const float* b1  = (const float*)d_in[3];
  const float* w2  = (const float*)d_in[4];
  const float* g2  = (const float*)d_in[5];
  const float* b2  = (const float*)d_in[6];
  const float* w3  = (const float*)d_in[7];
  const float* g3  = (const float*)d_in[8];
  const float* b3  = (const float*)d_in[9];
  const float* wp  = (const float*)d_in[10];
  const float* bp  = (const float*)d_in[11];
  const float* wcc = (const float*)d_in[12];
  const float* wcl = (const float*)d_in[13];
  float* out = (float*)d_out;
  float* ws  = (float*)d_ws;

  // persistent regions (float offsets)
  float* t1    = ws + 0;            // 3,145,728
  float* t2    = ws + 3145728;      // 1,572,864
  float* t3    = ws + 4718592;      // 3,145,728
  float* pc    = ws + 7864320;      //   602,112
  float* uu    = ws + 8466432;      // 5,419,008
  float* u2b   = ws + 13885440;     //   602,112
  unsigned short* uh2b = (unsigned short*)(ws + 14487552);  // 8,028,160 ushorts
  float* b2l   = ws + 22515712;     //   501,760
  float* scrC  = ws + 23017472;     //   501,760 (BN stats during convs, cpart during class)
  float* v2    = ws + 23519232;     //    10,240
  float* spart = ws + 23529472;     //     3,072
  float* U     = ws + 23533312;     // arena, 10,838,016 f32 (conv transients)
  __hip_bfloat16* uhc = (__hip_bfloat16*)(ws + 34371328);   // 43,352,064 bf16 (one 32-img chunk)

  // split/reordered weights live in dead `uu` region (dead until uu_gather)
  unsigned short* wh2 = (unsigned short*)(uu + 0);
  unsigned short* wl2 = (unsigned short*)(uu + 20736);
  unsigned short* wh3 = (unsigned short*)(uu + 41472);
  unsigned short* wl3 = (unsigned short*)(uu + 124416);
  unsigned short* whp = (unsigned short*)(uu + 207360);
  unsigned short* wlp = (unsigned short*)(uu + 373248);

  // phase transients in the U arena
  unsigned short* x2h = (unsigned short*)(U + 0);
  unsigned short* x2l = (unsigned short*)(U + 1775616);
  float*          part2 = U + 3551232;                    // 3x96x16384
  unsigned short* x3h = (unsigned short*)(U + 0);
  unsigned short* x3l = (unsigned short*)(U + 995328);
  unsigned short* xph = (unsigned short*)(U + 0);
  unsigned short* xpl = (unsigned short*)(U + 1572864);
  float*          partp = U + 3145728;                    // 8x192x3136

  const int B = 64;

  // merged weight splits
  split_w_all<<<2106,256,0,stream>>>(w2, w3, wp, wh2, wl2, wh3, wl3, whp, wlp);

  // conv1 + BN1 stats
  conv1_fused<<<2048,192,0,stream>>>(images, w1, t1);
  bn_partial<48,1024,8><<<48*8,256,0,stream>>>(t1, spart, B);

  // conv2: fused BN1-final+affine+ReLU+split (with halos), MFMA split-K=3, reduce+stats
  bn_split_nhwc2<48,32,32,1,8><<<64*34,256,0,stream>>>(t1, spart, g1, b1, x2h, x2l, 65536);
  conv_mfma<48,34,34,16,16,2,3><<<dim3(2,128,3),256,0,stream>>>(x2h, x2l, wh2, wl2, part2, 96, B);
  splitk_reduce<96,256,3,false,true><<<6144,256,0,stream>>>(part2, nullptr, t2, scrC, B);

  // conv3: fused BN2-final in split pass; direct NCHW write, stats via bn_partial
  bn_split_nhwc2<96,16,16,1,64><<<64*18,256,0,stream>>>(t2, scrC, g2, b2, x3h, x3l, 16384);
  conv_mfma<96,18,18,16,16,1,1><<<dim3(3,128,1),256,0,stream>>>(x3h, x3l, wh3, wl3, t3, 192, B);
  bn_partial<192,256,8><<<192*8,256,0,stream>>>(t3, spart, B);

  // primary caps conv (fused BN3-final in split pass) + bias, then squash
  bn_split_nhwc2<192,16,16,0,8><<<64*16,256,0,stream>>>(t3, spart, g3, b3, xph, xpl, 16384);
  conv_mfma<192,16,16,7,7,2,8><<<dim3(3,25,8),256,0,stream>>>(xph, xpl, whp, wlp, partp, 192, B);
  splitk_reduce<192,49,8,true,false><<<2352,256,0,stream>>>(partp, bp, pc, nullptr, B);
  squash_pc<<<196,256,0,stream>>>(pc, 50176);

  // uu gather
  uu_gather<<<21168,256,0,stream>>>(pc, uu, B);
  // ConvCaps einsum v5 (resident weights + wide staged stores) + register-stash routing
  for (int cb = 0; cb < 2; ++cb) {
    cc_einsum5<<<dim3(144,25),192,0,stream>>>(uu, wcc, uhc, cb*1568, 1568);
    cc_route<<<1568,384,0,stream>>>(uhc, u2b, cb*1568);
  }
  // Class caps einsum (bf16) + wave-local routing
  class_einsum<<<784,320,0,stream>>>(u2b, wcl, uh2b, B);
  cls_pass<0><<<dim3(64,7),256,0,stream>>>(uh2b, v2, b2l, scrC);
  cls_finish<<<64,160,0,stream>>>(scrC, v2, 0.1f);
  cls_pass<1><<<dim3(64,7),256,0,stream>>>(uh2b, v2, b2l, scrC);
  cls_finish<<<64,160,0,stream>>>(scrC, v2, 1.0f);
  cls_pass<2><<<dim3(64,7),256,0,stream>>>(uh2b, v2, b2l, scrC);
  cls_finish<<<64,160,0,stream>>>(scrC, out, 1.0f);
  (void)in_sizes; (void)n_in; (void)out_size; (void)ws_size;
}